// Round 11
// baseline (483.516 us; speedup 1.0000x reference)
//
#include <hip/hip_runtime.h>
#include <hip/hip_fp16.h>

#define N_NODES 100000
#define N_EDGES 1600000
#define HID 128
#define N_GRAPHS 512
#define NBK 196      // ceil(N_NODES/512) dst-buckets
#define SEG 8192     // edges per bhist/passA block

typedef _Float16 f16x8 __attribute__((ext_vector_type(8)));
typedef float f32x4 __attribute__((ext_vector_type(4)));

// ---------------- CSR build: bucket histogram -> scan -> 2-pass radix ----------------
// R6-R8: random 4B stores/atomics to HBM-shared lines cost a 64B line
// writeback per op (8 non-coherent XCD L2s churn ownership). Fix: counts in
// LDS; every global write region block-exclusive & coalesced.

__global__ void k_bhist(const int* __restrict__ dst, int e, int* __restrict__ bkcnt) {
    __shared__ int l[NBK];
    int tid = threadIdx.x;
    for (int i = tid; i < NBK; i += 256) l[i] = 0;
    __syncthreads();
    int base = blockIdx.x * SEG;
    int m = min(SEG, e - base);
    for (int i = tid; i < m; i += 256) atomicAdd(&l[dst[base + i] >> 9], 1);
    __syncthreads();
    for (int b = tid; b < NBK; b += 256)
        if (l[b]) atomicAdd(&bkcnt[b], l[b]);
}

__global__ void k_bscan(const int* __restrict__ bkcnt, int* __restrict__ bkoff,
                        int* __restrict__ bcur, int e) {
    __shared__ int s[256];
    int t = threadIdx.x;
    int v = (t < NBK) ? bkcnt[t] : 0;
    s[t] = v;
    __syncthreads();
    for (int off = 1; off < 256; off <<= 1) {
        int u = (t >= off) ? s[t - off] : 0;
        __syncthreads();
        s[t] += u;
        __syncthreads();
    }
    int excl = s[t] - v;
    if (t < NBK) { bkoff[t] = excl; bcur[t] = excl; }
    if (t == NBK - 1) bkoff[NBK] = excl + v;   // == e
}

__launch_bounds__(256) __global__
void k_passA(const int* __restrict__ ei, int* __restrict__ bcur,
             unsigned* __restrict__ pk, int e) {
    __shared__ int lcnt[NBK];
    __shared__ int lbase[NBK];
    int tid = threadIdx.x;
    int base = blockIdx.x * SEG;
    for (int i = tid; i < NBK; i += 256) lcnt[i] = 0;
    __syncthreads();
    int m = min(SEG, e - base);
    for (int i = tid; i < m; i += 256) {
        int d = ei[N_EDGES + base + i];
        atomicAdd(&lcnt[d >> 9], 1);
    }
    __syncthreads();
    for (int b = tid; b < NBK; b += 256)
        lbase[b] = lcnt[b] ? atomicAdd(&bcur[b], lcnt[b]) : 0;
    __syncthreads();
    for (int i = tid; i < m; i += 256) {
        int s = ei[base + i];
        int d = ei[N_EDGES + base + i];
        int pos = atomicAdd(&lbase[d >> 9], 1);
        pk[pos] = ((unsigned)s << 9) | (unsigned)(d & 511);   // s<2^17 fits
    }
}

__launch_bounds__(256) __global__
void k_passB(const unsigned* __restrict__ pk, const int* __restrict__ bkoff,
             int* __restrict__ rowptr, float* __restrict__ dis, float* __restrict__ dinv,
             int* __restrict__ csrc, int n, int e) {
    __shared__ int lcnt[512];
    __shared__ int lofs[512];
    __shared__ int sw[256];
    int b = blockIdx.x;
    int tid = threadIdx.x;
    int db0 = b * 512;
    int nd = min(512, n - db0);
    int pbeg = bkoff[b];
    int pend = bkoff[b + 1];
    lcnt[tid] = 0;
    lcnt[tid + 256] = 0;
    __syncthreads();
    for (int i = pbeg + tid; i < pend; i += 256) atomicAdd(&lcnt[pk[i] & 511], 1);
    __syncthreads();
    for (int j = tid; j < nd; j += 256) {
        float d = (float)(lcnt[j] + 1);
        dis[db0 + j] = rsqrtf(d);
        dinv[db0 + j] = 1.0f / d;
    }
    int a0 = lcnt[2 * tid];
    int a1 = lcnt[2 * tid + 1];
    int v = a0 + a1;
    sw[tid] = v;
    __syncthreads();
    for (int off = 1; off < 256; off <<= 1) {
        int u = (tid >= off) ? sw[tid - off] : 0;
        __syncthreads();
        sw[tid] += u;
        __syncthreads();
    }
    int excl = sw[tid] - v;
    lofs[2 * tid] = excl;
    lofs[2 * tid + 1] = excl + a0;
    __syncthreads();
    for (int j = tid; j < nd; j += 256) rowptr[db0 + j] = pbeg + lofs[j];
    if (db0 + nd == n && tid == 0) rowptr[n] = e;
    for (int j = tid; j < 512; j += 256) lcnt[j] = pbeg + lofs[j];
    __syncthreads();
    for (int i = pbeg + tid; i < pend; i += 256) {
        unsigned w = pk[i];
        int pos = atomicAdd(&lcnt[w & 511], 1);
        csrc[pos] = (int)(w >> 9);
    }
}

// ---------------- x padded to 8 channels (x8[i][7] = 0) ----------------

__global__ void k_padx(const float* __restrict__ x, float* __restrict__ x8, int n) {
    int i = blockIdx.x * 256 + threadIdx.x;
    if (i >= n * 8) return;
    int node = i >> 3;
    int k = i & 7;
    x8[i] = (k < 7) ? x[node * 7 + k] : 0.f;
}

// ---------------- layer-1 aggregation on RAW x (7ch, padded to 8) ----------------
// aggx = dinv*x + dis * sum dis[s]*x[s]. SIMPLE form (R10's shfl version gave
// a small systematic error — bisecting): 4 threads/node, thread owns float2
// channel-pair qq; serial loop over the node's edges. 400K threads, table is
// 3.2MB L2-resident; redundant csrc/dis reads are L2 hits.

__launch_bounds__(256) __global__
void k_gather7(const int* __restrict__ rowptr, const int* __restrict__ csrc,
               const float* __restrict__ dis, const float* __restrict__ dinv,
               const float2* __restrict__ x8v, float2* __restrict__ aggxv, int n) {
    int idx = blockIdx.x * 256 + threadIdx.x;
    int node = idx >> 2;
    if (node >= n) return;
    int qq = idx & 3;
    int beg = rowptr[node];
    int end = rowptr[node + 1];
    float dd = dis[node];
    float di = dinv[node];
    float2 acc = make_float2(0.f, 0.f);
    int j = beg;
    for (; j + 1 < end; j += 2) {
        int s0 = csrc[j];
        int s1 = csrc[j + 1];
        float w0 = dis[s0];
        float w1 = dis[s1];
        float2 v0 = x8v[(size_t)s0 * 4 + qq];
        float2 v1 = x8v[(size_t)s1 * 4 + qq];
        acc.x += v0.x * w0 + v1.x * w1;
        acc.y += v0.y * w0 + v1.y * w1;
    }
    if (j < end) {
        int s0 = csrc[j];
        float w0 = dis[s0];
        float2 v0 = x8v[(size_t)s0 * 4 + qq];
        acc.x += v0.x * w0;
        acc.y += v0.y * w0;
    }
    float2 ps = x8v[(size_t)node * 4 + qq];
    float2 r;
    r.x = ps.x * di + dd * acc.x;
    r.y = ps.y * di + dd * acc.y;
    aggxv[(size_t)node * 4 + qq] = r;
}

// ---------------- fused layer1+2 GEMM: hw2 = relu(aggx@W1 + b1) @ W2 ----------------
// Phase A (VALU): thread (rg=tid>>5, c4=tid&31) computes a1[row][4c4..] for 8
// rows with W1 column-slice held in 28 registers; relu+pack -> As (swizzled).
// Phase B: MFMA with W2^T staged once per block; two 64-row tiles per block.

__device__ __forceinline__ int swz(int row, int kByte) {
    return row * 256 + (kByte ^ ((row & 7) << 4));
}

__launch_bounds__(256) __global__
void k_l12(const float2* __restrict__ aggxv, const float* __restrict__ b1,
           const float* __restrict__ W1, const float* __restrict__ W2,
           __half* __restrict__ hwout, int n) {
    __shared__ __align__(16) _Float16 Wt[128 * 128];  // 32 KB (W2^T swizzled)
    __shared__ __align__(16) _Float16 As[64 * 128];   // 16 KB
    int tid = threadIdx.x;

    for (int i = tid; i < 128 * 128; i += 256) {
        int k = i >> 7;
        int nn = i & 127;
        *(_Float16*)((char*)Wt + swz(nn, k * 2)) = (_Float16)W2[i];
    }

    int rg = tid >> 5;         // 0..7: rows rg*8..rg*8+7
    int c4 = tid & 31;         // 4-channel group
    int col = c4 * 4;
    float4 w1k[7];
#pragma unroll
    for (int k = 0; k < 7; ++k) w1k[k] = *(const float4*)(W1 + k * 128 + col);
    float4 bb = *(const float4*)(b1 + col);

    int wv = tid >> 6;
    int lane = tid & 63;
    int lo16 = lane & 15;
    int hi4 = lane >> 4;

    for (int t = 0; t < 2; ++t) {
        if (t) __syncthreads();
#pragma unroll
        for (int rl = 0; rl < 8; ++rl) {
            int row = rg * 8 + rl;
            int grow = blockIdx.x * 128 + t * 64 + row;
            uint2 pk2 = make_uint2(0u, 0u);
            if (grow < n) {
                float2 a0 = aggxv[(size_t)grow * 4 + 0];
                float2 a1 = aggxv[(size_t)grow * 4 + 1];
                float2 a2 = aggxv[(size_t)grow * 4 + 2];
                float2 a3 = aggxv[(size_t)grow * 4 + 3];
                float4 acc = bb;
                acc.x += a0.x*w1k[0].x + a0.y*w1k[1].x + a1.x*w1k[2].x + a1.y*w1k[3].x
                       + a2.x*w1k[4].x + a2.y*w1k[5].x + a3.x*w1k[6].x;
                acc.y += a0.x*w1k[0].y + a0.y*w1k[1].y + a1.x*w1k[2].y + a1.y*w1k[3].y
                       + a2.x*w1k[4].y + a2.y*w1k[5].y + a3.x*w1k[6].y;
                acc.z += a0.x*w1k[0].z + a0.y*w1k[1].z + a1.x*w1k[2].z + a1.y*w1k[3].z
                       + a2.x*w1k[4].z + a2.y*w1k[5].z + a3.x*w1k[6].z;
                acc.w += a0.x*w1k[0].w + a0.y*w1k[1].w + a1.x*w1k[2].w + a1.y*w1k[3].w
                       + a2.x*w1k[4].w + a2.y*w1k[5].w + a3.x*w1k[6].w;
                __half2 h0 = __floats2half2_rn(fmaxf(acc.x, 0.f), fmaxf(acc.y, 0.f));
                __half2 h1 = __floats2half2_rn(fmaxf(acc.z, 0.f), fmaxf(acc.w, 0.f));
                pk2.x = *(unsigned*)&h0;
                pk2.y = *(unsigned*)&h1;
            }
            *(uint2*)((char*)As + swz(row, c4 * 8)) = pk2;
        }
        __syncthreads();

        f32x4 acc[8];
#pragma unroll
        for (int nt = 0; nt < 8; ++nt) acc[nt] = (f32x4){0.f, 0.f, 0.f, 0.f};
        const char* Ab = (const char*)As;
        const char* Bb = (const char*)Wt;
#pragma unroll
        for (int kt = 0; kt < 4; ++kt) {
            int kByte = kt * 64 + hi4 * 16;
            f16x8 af = *(const f16x8*)(Ab + swz(wv * 16 + lo16, kByte));
#pragma unroll
            for (int nt = 0; nt < 8; ++nt) {
                f16x8 bf = *(const f16x8*)(Bb + swz(nt * 16 + lo16, kByte));
                acc[nt] = __builtin_amdgcn_mfma_f32_16x16x32_f16(af, bf, acc[nt], 0, 0, 0);
            }
        }
        int rbase = blockIdx.x * 128 + t * 64 + wv * 16 + hi4 * 4;
#pragma unroll
        for (int nt = 0; nt < 8; ++nt) {
#pragma unroll
            for (int r = 0; r < 4; ++r) {
                int node = rbase + r;
                if (node < n)
                    hwout[(size_t)node * 128 + nt * 16 + lo16] = __float2half_rn(acc[nt][r]);
            }
        }
    }
}

// ---------------- gather aggregation (fp16 rows, 128ch), 8-deep unroll ----------------
// agg[d] = dinv[d]*hw[d] + dis[d] * sum_s dis[s]*hw[s]

__device__ __forceinline__ void acc8(uint2 p, float w, float4& a) {
    float2 lo = __half22float2(*(__half2*)&p.x);
    float2 hi = __half22float2(*(__half2*)&p.y);
    a.x += lo.x * w; a.y += lo.y * w; a.z += hi.x * w; a.w += hi.y * w;
}

__launch_bounds__(256) __global__
void k_gather(const int* __restrict__ rowptr, const int* __restrict__ csrc,
              const float* __restrict__ dis, const float* __restrict__ dinv,
              const uint2* __restrict__ hwv, uint2* __restrict__ aggv, int n) {
    int wid = blockIdx.x * 4 + (threadIdx.x >> 6);
    int lane = threadIdx.x & 63;
    int sub = lane >> 5;
    int c = lane & 31;
    int node = wid * 2 + sub;
    if (node >= n) return;

    int beg = rowptr[node];
    int end = rowptr[node + 1];
    int deg = end - beg;
    float dd = dis[node];
    float di = dinv[node];

    int sidx = 0;
    float wsc = 0.f;
    if (c < deg) {
        sidx = csrc[beg + c];
        wsc = dis[sidx];
    }

    int mown = deg < 32 ? deg : 32;
    int m = max(__shfl(mown, 0), __shfl(mown, 32));
    int sub32 = sub << 5;

    float4 a = make_float4(0.f, 0.f, 0.f, 0.f);
    int j = 0;
    for (; j + 7 < m; j += 8) {
        int s0 = __shfl(sidx, sub32 + j);     float w0 = __shfl(wsc, sub32 + j);
        int s1 = __shfl(sidx, sub32 + j + 1); float w1 = __shfl(wsc, sub32 + j + 1);
        int s2 = __shfl(sidx, sub32 + j + 2); float w2 = __shfl(wsc, sub32 + j + 2);
        int s3 = __shfl(sidx, sub32 + j + 3); float w3 = __shfl(wsc, sub32 + j + 3);
        int s4 = __shfl(sidx, sub32 + j + 4); float w4 = __shfl(wsc, sub32 + j + 4);
        int s5 = __shfl(sidx, sub32 + j + 5); float w5 = __shfl(wsc, sub32 + j + 5);
        int s6 = __shfl(sidx, sub32 + j + 6); float w6 = __shfl(wsc, sub32 + j + 6);
        int s7 = __shfl(sidx, sub32 + j + 7); float w7 = __shfl(wsc, sub32 + j + 7);
        uint2 p0 = hwv[(size_t)s0 * 32 + c];
        uint2 p1 = hwv[(size_t)s1 * 32 + c];
        uint2 p2 = hwv[(size_t)s2 * 32 + c];
        uint2 p3 = hwv[(size_t)s3 * 32 + c];
        uint2 p4 = hwv[(size_t)s4 * 32 + c];
        uint2 p5 = hwv[(size_t)s5 * 32 + c];
        uint2 p6 = hwv[(size_t)s6 * 32 + c];
        uint2 p7 = hwv[(size_t)s7 * 32 + c];
        acc8(p0, w0, a); acc8(p1, w1, a); acc8(p2, w2, a); acc8(p3, w3, a);
        acc8(p4, w4, a); acc8(p5, w5, a); acc8(p6, w6, a); acc8(p7, w7, a);
    }
    for (; j < m; ++j) {
        int s0 = __shfl(sidx, sub32 + j);
        float w0 = __shfl(wsc, sub32 + j);
        uint2 p0 = hwv[(size_t)s0 * 32 + c];
        acc8(p0, w0, a);
    }
    for (int jj = beg + 32; jj < end; ++jj) {
        int s0 = csrc[jj];
        float w0 = dis[s0];
        uint2 p0 = hwv[(size_t)s0 * 32 + c];
        acc8(p0, w0, a);
    }

    uint2 ps = hwv[(size_t)node * 32 + c];
    float2 slo = __half22float2(*(__half2*)&ps.x);
    float2 shi = __half22float2(*(__half2*)&ps.y);
    float4 r;
    r.x = slo.x * di + dd * a.x;
    r.y = slo.y * di + dd * a.y;
    r.z = shi.x * di + dd * a.z;
    r.w = shi.y * di + dd * a.w;
    __half2 lo = __floats2half2_rn(r.x, r.y);
    __half2 hi = __floats2half2_rn(r.z, r.w);
    uint2 o;
    o.x = *(unsigned*)&lo;
    o.y = *(unsigned*)&hi;
    aggv[(size_t)node * 32 + c] = o;
}

// ---------------- layer-3 gather fused with pooling ----------------
// agg3 row in registers -> relu(agg3+b3) -> atomicMax into pooled (payload-
// sized near-memory atomics; saves agg3 write + pool read + a launch).

__launch_bounds__(256) __global__
void k_gatherpool(const int* __restrict__ rowptr, const int* __restrict__ csrc,
                  const float* __restrict__ dis, const float* __restrict__ dinv,
                  const uint2* __restrict__ hwv, const float* __restrict__ b3,
                  const int* __restrict__ batch, unsigned* __restrict__ pooled, int n) {
    int wid = blockIdx.x * 4 + (threadIdx.x >> 6);
    int lane = threadIdx.x & 63;
    int sub = lane >> 5;
    int c = lane & 31;
    int node = wid * 2 + sub;
    if (node >= n) return;

    int beg = rowptr[node];
    int end = rowptr[node + 1];
    int deg = end - beg;
    float dd = dis[node];
    float di = dinv[node];

    int sidx = 0;
    float wsc = 0.f;
    if (c < deg) {
        sidx = csrc[beg + c];
        wsc = dis[sidx];
    }

    int mown = deg < 32 ? deg : 32;
    int m = max(__shfl(mown, 0), __shfl(mown, 32));
    int sub32 = sub << 5;

    float4 a = make_float4(0.f, 0.f, 0.f, 0.f);
    int j = 0;
    for (; j + 7 < m; j += 8) {
        int s0 = __shfl(sidx, sub32 + j);     float w0 = __shfl(wsc, sub32 + j);
        int s1 = __shfl(sidx, sub32 + j + 1); float w1 = __shfl(wsc, sub32 + j + 1);
        int s2 = __shfl(sidx, sub32 + j + 2); float w2 = __shfl(wsc, sub32 + j + 2);
        int s3 = __shfl(sidx, sub32 + j + 3); float w3 = __shfl(wsc, sub32 + j + 3);
        int s4 = __shfl(sidx, sub32 + j + 4); float w4 = __shfl(wsc, sub32 + j + 4);
        int s5 = __shfl(sidx, sub32 + j + 5); float w5 = __shfl(wsc, sub32 + j + 5);
        int s6 = __shfl(sidx, sub32 + j + 6); float w6 = __shfl(wsc, sub32 + j + 6);
        int s7 = __shfl(sidx, sub32 + j + 7); float w7 = __shfl(wsc, sub32 + j + 7);
        uint2 p0 = hwv[(size_t)s0 * 32 + c];
        uint2 p1 = hwv[(size_t)s1 * 32 + c];
        uint2 p2 = hwv[(size_t)s2 * 32 + c];
        uint2 p3 = hwv[(size_t)s3 * 32 + c];
        uint2 p4 = hwv[(size_t)s4 * 32 + c];
        uint2 p5 = hwv[(size_t)s5 * 32 + c];
        uint2 p6 = hwv[(size_t)s6 * 32 + c];
        uint2 p7 = hwv[(size_t)s7 * 32 + c];
        acc8(p0, w0, a); acc8(p1, w1, a); acc8(p2, w2, a); acc8(p3, w3, a);
        acc8(p4, w4, a); acc8(p5, w5, a); acc8(p6, w6, a); acc8(p7, w7, a);
    }
    for (; j < m; ++j) {
        int s0 = __shfl(sidx, sub32 + j);
        float w0 = __shfl(wsc, sub32 + j);
        uint2 p0 = hwv[(size_t)s0 * 32 + c];
        acc8(p0, w0, a);
    }
    for (int jj = beg + 32; jj < end; ++jj) {
        int s0 = csrc[jj];
        float w0 = dis[s0];
        uint2 p0 = hwv[(size_t)s0 * 32 + c];
        acc8(p0, w0, a);
    }

    uint2 ps = hwv[(size_t)node * 32 + c];
    float2 slo = __half22float2(*(__half2*)&ps.x);
    float2 shi = __half22float2(*(__half2*)&ps.y);
    float4 bb = *(const float4*)(b3 + c * 4);
    float4 r;
    r.x = fmaxf(slo.x * di + dd * a.x + bb.x, 0.f);
    r.y = fmaxf(slo.y * di + dd * a.y + bb.y, 0.f);
    r.z = fmaxf(shi.x * di + dd * a.z + bb.z, 0.f);
    r.w = fmaxf(shi.y * di + dd * a.w + bb.w, 0.f);
    int g = batch[node];
    unsigned* pp = pooled + (size_t)g * 128 + c * 4;
    atomicMax(pp + 0, __float_as_uint(r.x));
    atomicMax(pp + 1, __float_as_uint(r.y));
    atomicMax(pp + 2, __float_as_uint(r.z));
    atomicMax(pp + 3, __float_as_uint(r.w));
}

// ---------------- MFMA GEMM: hwout = relu(aggin + b) @ W  (fp16 in/out) ----------------

__launch_bounds__(256) __global__
void k_gemm_mfma(const __half* __restrict__ aggin, const float* __restrict__ b,
                 const float* __restrict__ W, __half* __restrict__ hwout, int n) {
    __shared__ __align__(16) _Float16 Wt[128 * 128];  // 32 KB
    __shared__ __align__(16) _Float16 As[64 * 128];   // 16 KB
    int tid = threadIdx.x;

    for (int i = tid; i < 128 * 128; i += 256) {
        int k = i >> 7;
        int nn = i & 127;
        *(_Float16*)((char*)Wt + swz(nn, k * 2)) = (_Float16)W[i];
    }

    int row = tid >> 2;
    int q = tid & 3;
    int wv = tid >> 6;
    int lane = tid & 63;
    int lo16 = lane & 15;
    int hi4 = lane >> 4;

    for (int t = 0; t < 2; ++t) {
        if (t) __syncthreads();
        int grow = blockIdx.x * 128 + t * 64 + row;
#pragma unroll
        for (int j = 0; j < 4; ++j) {
            int c0 = q * 32 + j * 8;
            uint4 pk = make_uint4(0u, 0u, 0u, 0u);
            if (grow < n) {
                uint4 p = *(const uint4*)(aggin + (size_t)grow * 128 + c0);
                float4 bA = *(const float4*)(b + c0);
                float4 bB = *(const float4*)(b + c0 + 4);
                float2 t0 = __half22float2(*(const __half2*)&p.x);
                float2 t1 = __half22float2(*(const __half2*)&p.y);
                float2 t2 = __half22float2(*(const __half2*)&p.z);
                float2 t3 = __half22float2(*(const __half2*)&p.w);
                __half2 h0 = __floats2half2_rn(fmaxf(t0.x + bA.x, 0.f), fmaxf(t0.y + bA.y, 0.f));
                __half2 h1 = __floats2half2_rn(fmaxf(t1.x + bA.z, 0.f), fmaxf(t1.y + bA.w, 0.f));
                __half2 h2 = __floats2half2_rn(fmaxf(t2.x + bB.x, 0.f), fmaxf(t2.y + bB.y, 0.f));
                __half2 h3 = __floats2half2_rn(fmaxf(t3.x + bB.z, 0.f), fmaxf(t3.y + bB.w, 0.f));
                pk.x = *(unsigned*)&h0; pk.y = *(unsigned*)&h1;
                pk.z = *(unsigned*)&h2; pk.w = *(unsigned*)&h3;
            }
            *(uint4*)((char*)As + swz(row, c0 * 2)) = pk;
        }
        __syncthreads();

        f32x4 acc[8];
#pragma unroll
        for (int nt = 0; nt < 8; ++nt) acc[nt] = (f32x4){0.f, 0.f, 0.f, 0.f};

        const char* Ab = (const char*)As;
        const char* Bb = (const char*)Wt;
#pragma unroll
        for (int kt = 0; kt < 4; ++kt) {
            int kByte = kt * 64 + hi4 * 16;
            f16x8 af = *(const f16x8*)(Ab + swz(wv * 16 + lo16, kByte));
#pragma unroll
            for (int nt = 0; nt < 8; ++nt) {
                f16x8 bf = *(const f16x8*)(Bb + swz(nt * 16 + lo16, kByte));
                acc[nt] = __builtin_amdgcn_mfma_f32_16x16x32_f16(af, bf, acc[nt], 0, 0, 0);
            }
        }

        int rbase = blockIdx.x * 128 + t * 64 + wv * 16 + hi4 * 4;
#pragma unroll
        for (int nt = 0; nt < 8; ++nt) {
#pragma unroll
            for (int r = 0; r < 4; ++r) {
                int node = rbase + r;
                if (node < n)
                    hwout[(size_t)node * 128 + nt * 16 + lo16] = __float2half_rn(acc[nt][r]);
            }
        }
    }
}

// ---------------- head: out[g] = pooled[g] @ Wl + bl ----------------

__global__ void k_final(const float* __restrict__ pooled, const float* __restrict__ Wl,
                        const float* __restrict__ bl, float* __restrict__ out) {
    int g = blockIdx.x;
    int t = threadIdx.x;  // 64 threads
    float p0 = pooled[(size_t)g * 128 + t];
    float p1 = pooled[(size_t)g * 128 + t + 64];
    float a0 = p0 * Wl[t * 2 + 0] + p1 * Wl[(t + 64) * 2 + 0];
    float a1 = p0 * Wl[t * 2 + 1] + p1 * Wl[(t + 64) * 2 + 1];
#pragma unroll
    for (int off = 32; off > 0; off >>= 1) {
        a0 += __shfl_down(a0, off);
        a1 += __shfl_down(a1, off);
    }
    if (t == 0) {
        out[g * 2 + 0] = a0 + bl[0];
        out[g * 2 + 1] = a1 + bl[1];
    }
}

// ---------------- launch ----------------

extern "C" void kernel_launch(void* const* d_in, const int* in_sizes, int n_in,
                              void* d_out, int out_size, void* d_ws, size_t ws_size,
                              hipStream_t stream) {
    const float* x  = (const float*)d_in[0];
    const int*   ei = (const int*)d_in[1];
    const int*   batch = (const int*)d_in[2];
    const float* W1 = (const float*)d_in[3];
    const float* b1 = (const float*)d_in[4];
    const float* W2 = (const float*)d_in[5];
    const float* b2 = (const float*)d_in[6];
    const float* W3 = (const float*)d_in[7];
    const float* b3 = (const float*)d_in[8];
    const float* Wl = (const float*)d_in[9];
    const float* bl = (const float*)d_in[10];
    float* out = (float*)d_out;

    const int N = N_NODES, E = N_EDGES;

    // workspace layout
    char* ws = (char*)d_ws;
    __half* bufA = (__half*)ws;                             // N*128 fp16 (hw)
    __half* bufB = bufA + (size_t)N * 128;                  // N*128 fp16 (agg)
    unsigned* pooled = (unsigned*)(bufB + (size_t)N * 128); // G*128
    float* dis  = (float*)(pooled + (size_t)N_GRAPHS * 128);
    float* dinv = dis + N;
    int*   rowptr = (int*)(dinv + N);                       // N+1
    int*   bkcnt  = rowptr + N + 2;                         // NBK
    int*   bkoff  = bkcnt + 256;                            // NBK+1
    int*   bcur   = bkoff + 256;                            // NBK
    int*   csrc   = bcur + 256;                             // E
    unsigned* pk  = (unsigned*)(csrc + E);                  // E (dead after passB)
    float* x8   = (float*)pk;                               // N*8 (aliases pk)
    float* aggx = x8 + (size_t)N * 8;                       // N*8 (aliases pk)

    // CSR build + norms (bucket hist -> scan -> radix passA/passB)
    hipMemsetAsync(bkcnt, 0, NBK * sizeof(int), stream);
    int nseg = (E + SEG - 1) / SEG;   // 196
    k_bhist<<<nseg, 256, 0, stream>>>(ei + E, E, bkcnt);
    k_bscan<<<1, 256, 0, stream>>>(bkcnt, bkoff, bcur, E);
    k_passA<<<nseg, 256, 0, stream>>>(ei, bcur, pk, E);
    k_passB<<<NBK, 256, 0, stream>>>(pk, bkoff, rowptr, dis, dinv, csrc, N, E);

    int ggrid = (N + 7) / 8;           // 2 nodes/wave, 4 waves/block
    int mfma_grid = (N + 127) / 128;   // 782

    // layer 1: aggregate raw x (7ch), then fused (aggx@W1 -> relu -> @W2)
    k_padx<<<(N * 8 + 255) / 256, 256, 0, stream>>>(x, x8, N);
    k_gather7<<<(N * 4 + 255) / 256, 256, 0, stream>>>(rowptr, csrc, dis, dinv,
                                                       (const float2*)x8, (float2*)aggx, N);
    k_l12<<<mfma_grid, 256, 0, stream>>>((const float2*)aggx, b1, W1, W2, bufA, N);

    // layer 2
    k_gather<<<ggrid, 256, 0, stream>>>(rowptr, csrc, dis, dinv,
                                        (const uint2*)bufA, (uint2*)bufB, N);
    k_gemm_mfma<<<mfma_grid, 256, 0, stream>>>(bufB, b2, W3, bufA, N);

    // layer 3: gather fused with pooling
    hipMemsetAsync(pooled, 0, (size_t)N_GRAPHS * 128 * sizeof(unsigned), stream);
    k_gatherpool<<<ggrid, 256, 0, stream>>>(rowptr, csrc, dis, dinv,
                                            (const uint2*)bufA, b3, batch, pooled, N);

    // head
    k_final<<<N_GRAPHS, 64, 0, stream>>>((const float*)pooled, Wl, bl, out);
}

// Round 12
// 391.167 us; speedup vs baseline: 1.2361x; 1.2361x over previous
//
#include <hip/hip_runtime.h>
#include <hip/hip_fp16.h>

#define N_NODES 100000
#define N_EDGES 1600000
#define HID 128
#define N_GRAPHS 512
#define NBK 196      // ceil(N_NODES/512) dst-buckets
#define SEG 8192     // edges per bhist/passA block

typedef _Float16 f16x8 __attribute__((ext_vector_type(8)));
typedef float f32x4 __attribute__((ext_vector_type(4)));

// ---------------- CSR build: bucket histogram -> scan -> 2-pass radix ----------------
// R6-R8: random 4B stores/atomics to HBM-shared lines cost a 64B line
// writeback per op (8 non-coherent XCD L2s churn ownership). Fix: counts in
// LDS; every global write region block-exclusive & coalesced.

__global__ void k_bhist(const int* __restrict__ dst, int e, int* __restrict__ bkcnt) {
    __shared__ int l[NBK];
    int tid = threadIdx.x;
    for (int i = tid; i < NBK; i += 256) l[i] = 0;
    __syncthreads();
    int base = blockIdx.x * SEG;
    int m = min(SEG, e - base);
    for (int i = tid; i < m; i += 256) atomicAdd(&l[dst[base + i] >> 9], 1);
    __syncthreads();
    for (int b = tid; b < NBK; b += 256)
        if (l[b]) atomicAdd(&bkcnt[b], l[b]);
}

__global__ void k_bscan(const int* __restrict__ bkcnt, int* __restrict__ bkoff,
                        int* __restrict__ bcur, int e) {
    __shared__ int s[256];
    int t = threadIdx.x;
    int v = (t < NBK) ? bkcnt[t] : 0;
    s[t] = v;
    __syncthreads();
    for (int off = 1; off < 256; off <<= 1) {
        int u = (t >= off) ? s[t - off] : 0;
        __syncthreads();
        s[t] += u;
        __syncthreads();
    }
    int excl = s[t] - v;
    if (t < NBK) { bkoff[t] = excl; bcur[t] = excl; }
    if (t == NBK - 1) bkoff[NBK] = excl + v;   // == e
}

__launch_bounds__(256) __global__
void k_passA(const int* __restrict__ ei, int* __restrict__ bcur,
             unsigned* __restrict__ pk, int e) {
    __shared__ int lcnt[NBK];
    __shared__ int lbase[NBK];
    int tid = threadIdx.x;
    int base = blockIdx.x * SEG;
    for (int i = tid; i < NBK; i += 256) lcnt[i] = 0;
    __syncthreads();
    int m = min(SEG, e - base);
    for (int i = tid; i < m; i += 256) {
        int d = ei[N_EDGES + base + i];
        atomicAdd(&lcnt[d >> 9], 1);
    }
    __syncthreads();
    for (int b = tid; b < NBK; b += 256)
        lbase[b] = lcnt[b] ? atomicAdd(&bcur[b], lcnt[b]) : 0;
    __syncthreads();
    for (int i = tid; i < m; i += 256) {
        int s = ei[base + i];
        int d = ei[N_EDGES + base + i];
        int pos = atomicAdd(&lbase[d >> 9], 1);
        pk[pos] = ((unsigned)s << 9) | (unsigned)(d & 511);   // s<2^17 fits
    }
}

__launch_bounds__(256) __global__
void k_passB(const unsigned* __restrict__ pk, const int* __restrict__ bkoff,
             int* __restrict__ rowptr, float* __restrict__ dis, float* __restrict__ dinv,
             int* __restrict__ csrc, int n, int e) {
    __shared__ int lcnt[512];
    __shared__ int lofs[512];
    __shared__ int sw[256];
    int b = blockIdx.x;
    int tid = threadIdx.x;
    int db0 = b * 512;
    int nd = min(512, n - db0);
    int pbeg = bkoff[b];
    int pend = bkoff[b + 1];
    lcnt[tid] = 0;
    lcnt[tid + 256] = 0;
    __syncthreads();
    for (int i = pbeg + tid; i < pend; i += 256) atomicAdd(&lcnt[pk[i] & 511], 1);
    __syncthreads();
    for (int j = tid; j < nd; j += 256) {
        float d = (float)(lcnt[j] + 1);
        dis[db0 + j] = rsqrtf(d);
        dinv[db0 + j] = 1.0f / d;
    }
    int a0 = lcnt[2 * tid];
    int a1 = lcnt[2 * tid + 1];
    int v = a0 + a1;
    sw[tid] = v;
    __syncthreads();
    for (int off = 1; off < 256; off <<= 1) {
        int u = (tid >= off) ? sw[tid - off] : 0;
        __syncthreads();
        sw[tid] += u;
        __syncthreads();
    }
    int excl = sw[tid] - v;
    lofs[2 * tid] = excl;
    lofs[2 * tid + 1] = excl + a0;
    __syncthreads();
    for (int j = tid; j < nd; j += 256) rowptr[db0 + j] = pbeg + lofs[j];
    if (db0 + nd == n && tid == 0) rowptr[n] = e;
    for (int j = tid; j < 512; j += 256) lcnt[j] = pbeg + lofs[j];
    __syncthreads();
    for (int i = pbeg + tid; i < pend; i += 256) {
        unsigned w = pk[i];
        int pos = atomicAdd(&lcnt[w & 511], 1);
        csrc[pos] = (int)(w >> 9);
    }
}

// ---------------- x padded to 8 channels (x8[i][7] = 0) ----------------

__global__ void k_padx(const float* __restrict__ x, float* __restrict__ x8, int n) {
    int i = blockIdx.x * 256 + threadIdx.x;
    if (i >= n * 8) return;
    int node = i >> 3;
    int k = i & 7;
    x8[i] = (k < 7) ? x[node * 7 + k] : 0.f;
}

// ---------------- layer-1 aggregation on RAW x (7ch, padded to 8) ----------------
// GCN aggregation commutes with the linear map: agg(x@W1) = agg(x)@W1, so
// layer-1 gathers 32B/node-row (L2-resident) instead of 256B. Simple form:
// 4 threads/node, thread owns float2 channel-pair qq; serial edge loop.

__launch_bounds__(256) __global__
void k_gather7(const int* __restrict__ rowptr, const int* __restrict__ csrc,
               const float* __restrict__ dis, const float* __restrict__ dinv,
               const float2* __restrict__ x8v, float2* __restrict__ aggxv, int n) {
    int idx = blockIdx.x * 256 + threadIdx.x;
    int node = idx >> 2;
    if (node >= n) return;
    int qq = idx & 3;
    int beg = rowptr[node];
    int end = rowptr[node + 1];
    float dd = dis[node];
    float di = dinv[node];
    float2 acc = make_float2(0.f, 0.f);
    int j = beg;
    for (; j + 1 < end; j += 2) {
        int s0 = csrc[j];
        int s1 = csrc[j + 1];
        float w0 = dis[s0];
        float w1 = dis[s1];
        float2 v0 = x8v[(size_t)s0 * 4 + qq];
        float2 v1 = x8v[(size_t)s1 * 4 + qq];
        acc.x += v0.x * w0 + v1.x * w1;
        acc.y += v0.y * w0 + v1.y * w1;
    }
    if (j < end) {
        int s0 = csrc[j];
        float w0 = dis[s0];
        float2 v0 = x8v[(size_t)s0 * 4 + qq];
        acc.x += v0.x * w0;
        acc.y += v0.y * w0;
    }
    float2 ps = x8v[(size_t)node * 4 + qq];
    float2 r;
    r.x = ps.x * di + dd * acc.x;
    r.y = ps.y * di + dd * acc.y;
    aggxv[(size_t)node * 4 + qq] = r;
}

// ---------------- fused layer1+2 GEMM: hw2 = relu(aggx@W1 + b1) @ W2 ----------------

__device__ __forceinline__ int swz(int row, int kByte) {
    return row * 256 + (kByte ^ ((row & 7) << 4));
}

__launch_bounds__(256) __global__
void k_l12(const float2* __restrict__ aggxv, const float* __restrict__ b1,
           const float* __restrict__ W1, const float* __restrict__ W2,
           __half* __restrict__ hwout, int n) {
    __shared__ __align__(16) _Float16 Wt[128 * 128];  // 32 KB (W2^T swizzled)
    __shared__ __align__(16) _Float16 As[64 * 128];   // 16 KB
    int tid = threadIdx.x;

    for (int i = tid; i < 128 * 128; i += 256) {
        int k = i >> 7;
        int nn = i & 127;
        *(_Float16*)((char*)Wt + swz(nn, k * 2)) = (_Float16)W2[i];
    }

    int rg = tid >> 5;         // 0..7: rows rg*8..rg*8+7
    int c4 = tid & 31;         // 4-channel group
    int col = c4 * 4;
    float4 w1k[7];
#pragma unroll
    for (int k = 0; k < 7; ++k) w1k[k] = *(const float4*)(W1 + k * 128 + col);
    float4 bb = *(const float4*)(b1 + col);

    int wv = tid >> 6;
    int lane = tid & 63;
    int lo16 = lane & 15;
    int hi4 = lane >> 4;

    for (int t = 0; t < 2; ++t) {
        if (t) __syncthreads();
#pragma unroll
        for (int rl = 0; rl < 8; ++rl) {
            int row = rg * 8 + rl;
            int grow = blockIdx.x * 128 + t * 64 + row;
            uint2 pk2 = make_uint2(0u, 0u);
            if (grow < n) {
                float2 a0 = aggxv[(size_t)grow * 4 + 0];
                float2 a1 = aggxv[(size_t)grow * 4 + 1];
                float2 a2 = aggxv[(size_t)grow * 4 + 2];
                float2 a3 = aggxv[(size_t)grow * 4 + 3];
                float4 acc = bb;
                acc.x += a0.x*w1k[0].x + a0.y*w1k[1].x + a1.x*w1k[2].x + a1.y*w1k[3].x
                       + a2.x*w1k[4].x + a2.y*w1k[5].x + a3.x*w1k[6].x;
                acc.y += a0.x*w1k[0].y + a0.y*w1k[1].y + a1.x*w1k[2].y + a1.y*w1k[3].y
                       + a2.x*w1k[4].y + a2.y*w1k[5].y + a3.x*w1k[6].y;
                acc.z += a0.x*w1k[0].z + a0.y*w1k[1].z + a1.x*w1k[2].z + a1.y*w1k[3].z
                       + a2.x*w1k[4].z + a2.y*w1k[5].z + a3.x*w1k[6].z;
                acc.w += a0.x*w1k[0].w + a0.y*w1k[1].w + a1.x*w1k[2].w + a1.y*w1k[3].w
                       + a2.x*w1k[4].w + a2.y*w1k[5].w + a3.x*w1k[6].w;
                __half2 h0 = __floats2half2_rn(fmaxf(acc.x, 0.f), fmaxf(acc.y, 0.f));
                __half2 h1 = __floats2half2_rn(fmaxf(acc.z, 0.f), fmaxf(acc.w, 0.f));
                pk2.x = *(unsigned*)&h0;
                pk2.y = *(unsigned*)&h1;
            }
            *(uint2*)((char*)As + swz(row, c4 * 8)) = pk2;
        }
        __syncthreads();

        f32x4 acc[8];
#pragma unroll
        for (int nt = 0; nt < 8; ++nt) acc[nt] = (f32x4){0.f, 0.f, 0.f, 0.f};
        const char* Ab = (const char*)As;
        const char* Bb = (const char*)Wt;
#pragma unroll
        for (int kt = 0; kt < 4; ++kt) {
            int kByte = kt * 64 + hi4 * 16;
            f16x8 af = *(const f16x8*)(Ab + swz(wv * 16 + lo16, kByte));
#pragma unroll
            for (int nt = 0; nt < 8; ++nt) {
                f16x8 bf = *(const f16x8*)(Bb + swz(nt * 16 + lo16, kByte));
                acc[nt] = __builtin_amdgcn_mfma_f32_16x16x32_f16(af, bf, acc[nt], 0, 0, 0);
            }
        }
        int rbase = blockIdx.x * 128 + t * 64 + wv * 16 + hi4 * 4;
#pragma unroll
        for (int nt = 0; nt < 8; ++nt) {
#pragma unroll
            for (int r = 0; r < 4; ++r) {
                int node = rbase + r;
                if (node < n)
                    hwout[(size_t)node * 128 + nt * 16 + lo16] = __float2half_rn(acc[nt][r]);
            }
        }
    }
}

// ---------------- gather aggregation (fp16 rows, 128ch), 8-deep unroll ----------------
// agg[d] = dinv[d]*hw[d] + dis[d] * sum_s dis[s]*hw[s]
// R11 lesson: do NOT fuse contended atomics into this kernel — the pooled-row
// atomicMax stream halves effective read throughput (197 vs 61+~15 us split).

__device__ __forceinline__ void acc8(uint2 p, float w, float4& a) {
    float2 lo = __half22float2(*(__half2*)&p.x);
    float2 hi = __half22float2(*(__half2*)&p.y);
    a.x += lo.x * w; a.y += lo.y * w; a.z += hi.x * w; a.w += hi.y * w;
}

__launch_bounds__(256) __global__
void k_gather(const int* __restrict__ rowptr, const int* __restrict__ csrc,
              const float* __restrict__ dis, const float* __restrict__ dinv,
              const uint2* __restrict__ hwv, uint2* __restrict__ aggv, int n) {
    int wid = blockIdx.x * 4 + (threadIdx.x >> 6);
    int lane = threadIdx.x & 63;
    int sub = lane >> 5;
    int c = lane & 31;
    int node = wid * 2 + sub;
    if (node >= n) return;

    int beg = rowptr[node];
    int end = rowptr[node + 1];
    int deg = end - beg;
    float dd = dis[node];
    float di = dinv[node];

    int sidx = 0;
    float wsc = 0.f;
    if (c < deg) {
        sidx = csrc[beg + c];
        wsc = dis[sidx];
    }

    int mown = deg < 32 ? deg : 32;
    int m = max(__shfl(mown, 0), __shfl(mown, 32));
    int sub32 = sub << 5;

    float4 a = make_float4(0.f, 0.f, 0.f, 0.f);
    int j = 0;
    for (; j + 7 < m; j += 8) {
        int s0 = __shfl(sidx, sub32 + j);     float w0 = __shfl(wsc, sub32 + j);
        int s1 = __shfl(sidx, sub32 + j + 1); float w1 = __shfl(wsc, sub32 + j + 1);
        int s2 = __shfl(sidx, sub32 + j + 2); float w2 = __shfl(wsc, sub32 + j + 2);
        int s3 = __shfl(sidx, sub32 + j + 3); float w3 = __shfl(wsc, sub32 + j + 3);
        int s4 = __shfl(sidx, sub32 + j + 4); float w4 = __shfl(wsc, sub32 + j + 4);
        int s5 = __shfl(sidx, sub32 + j + 5); float w5 = __shfl(wsc, sub32 + j + 5);
        int s6 = __shfl(sidx, sub32 + j + 6); float w6 = __shfl(wsc, sub32 + j + 6);
        int s7 = __shfl(sidx, sub32 + j + 7); float w7 = __shfl(wsc, sub32 + j + 7);
        uint2 p0 = hwv[(size_t)s0 * 32 + c];
        uint2 p1 = hwv[(size_t)s1 * 32 + c];
        uint2 p2 = hwv[(size_t)s2 * 32 + c];
        uint2 p3 = hwv[(size_t)s3 * 32 + c];
        uint2 p4 = hwv[(size_t)s4 * 32 + c];
        uint2 p5 = hwv[(size_t)s5 * 32 + c];
        uint2 p6 = hwv[(size_t)s6 * 32 + c];
        uint2 p7 = hwv[(size_t)s7 * 32 + c];
        acc8(p0, w0, a); acc8(p1, w1, a); acc8(p2, w2, a); acc8(p3, w3, a);
        acc8(p4, w4, a); acc8(p5, w5, a); acc8(p6, w6, a); acc8(p7, w7, a);
    }
    for (; j < m; ++j) {
        int s0 = __shfl(sidx, sub32 + j);
        float w0 = __shfl(wsc, sub32 + j);
        uint2 p0 = hwv[(size_t)s0 * 32 + c];
        acc8(p0, w0, a);
    }
    for (int jj = beg + 32; jj < end; ++jj) {
        int s0 = csrc[jj];
        float w0 = dis[s0];
        uint2 p0 = hwv[(size_t)s0 * 32 + c];
        acc8(p0, w0, a);
    }

    uint2 ps = hwv[(size_t)node * 32 + c];
    float2 slo = __half22float2(*(__half2*)&ps.x);
    float2 shi = __half22float2(*(__half2*)&ps.y);
    float4 r;
    r.x = slo.x * di + dd * a.x;
    r.y = slo.y * di + dd * a.y;
    r.z = shi.x * di + dd * a.z;
    r.w = shi.y * di + dd * a.w;
    __half2 lo = __floats2half2_rn(r.x, r.y);
    __half2 hi = __floats2half2_rn(r.z, r.w);
    uint2 o;
    o.x = *(unsigned*)&lo;
    o.y = *(unsigned*)&hi;
    aggv[(size_t)node * 32 + c] = o;
}

// ---------------- MFMA GEMM: hwout = relu(aggin + b) @ W  (fp16 in/out) ----------------

__launch_bounds__(256) __global__
void k_gemm_mfma(const __half* __restrict__ aggin, const float* __restrict__ b,
                 const float* __restrict__ W, __half* __restrict__ hwout, int n) {
    __shared__ __align__(16) _Float16 Wt[128 * 128];  // 32 KB
    __shared__ __align__(16) _Float16 As[64 * 128];   // 16 KB
    int tid = threadIdx.x;

    for (int i = tid; i < 128 * 128; i += 256) {
        int k = i >> 7;
        int nn = i & 127;
        *(_Float16*)((char*)Wt + swz(nn, k * 2)) = (_Float16)W[i];
    }

    int row = tid >> 2;
    int q = tid & 3;
    int wv = tid >> 6;
    int lane = tid & 63;
    int lo16 = lane & 15;
    int hi4 = lane >> 4;

    for (int t = 0; t < 2; ++t) {
        if (t) __syncthreads();
        int grow = blockIdx.x * 128 + t * 64 + row;
#pragma unroll
        for (int j = 0; j < 4; ++j) {
            int c0 = q * 32 + j * 8;
            uint4 pk = make_uint4(0u, 0u, 0u, 0u);
            if (grow < n) {
                uint4 p = *(const uint4*)(aggin + (size_t)grow * 128 + c0);
                float4 bA = *(const float4*)(b + c0);
                float4 bB = *(const float4*)(b + c0 + 4);
                float2 t0 = __half22float2(*(const __half2*)&p.x);
                float2 t1 = __half22float2(*(const __half2*)&p.y);
                float2 t2 = __half22float2(*(const __half2*)&p.z);
                float2 t3 = __half22float2(*(const __half2*)&p.w);
                __half2 h0 = __floats2half2_rn(fmaxf(t0.x + bA.x, 0.f), fmaxf(t0.y + bA.y, 0.f));
                __half2 h1 = __floats2half2_rn(fmaxf(t1.x + bA.z, 0.f), fmaxf(t1.y + bA.w, 0.f));
                __half2 h2 = __floats2half2_rn(fmaxf(t2.x + bB.x, 0.f), fmaxf(t2.y + bB.y, 0.f));
                __half2 h3 = __floats2half2_rn(fmaxf(t3.x + bB.z, 0.f), fmaxf(t3.y + bB.w, 0.f));
                pk.x = *(unsigned*)&h0; pk.y = *(unsigned*)&h1;
                pk.z = *(unsigned*)&h2; pk.w = *(unsigned*)&h3;
            }
            *(uint4*)((char*)As + swz(row, c0 * 2)) = pk;
        }
        __syncthreads();

        f32x4 acc[8];
#pragma unroll
        for (int nt = 0; nt < 8; ++nt) acc[nt] = (f32x4){0.f, 0.f, 0.f, 0.f};

        const char* Ab = (const char*)As;
        const char* Bb = (const char*)Wt;
#pragma unroll
        for (int kt = 0; kt < 4; ++kt) {
            int kByte = kt * 64 + hi4 * 16;
            f16x8 af = *(const f16x8*)(Ab + swz(wv * 16 + lo16, kByte));
#pragma unroll
            for (int nt = 0; nt < 8; ++nt) {
                f16x8 bf = *(const f16x8*)(Bb + swz(nt * 16 + lo16, kByte));
                acc[nt] = __builtin_amdgcn_mfma_f32_16x16x32_f16(af, bf, acc[nt], 0, 0, 0);
            }
        }

        int rbase = blockIdx.x * 128 + t * 64 + wv * 16 + hi4 * 4;
#pragma unroll
        for (int nt = 0; nt < 8; ++nt) {
#pragma unroll
            for (int r = 0; r < 4; ++r) {
                int node = rbase + r;
                if (node < n)
                    hwout[(size_t)node * 128 + nt * 16 + lo16] = __float2half_rn(acc[nt][r]);
            }
        }
    }
}

// ---------------- pooling: segment_max(relu(agg+b)) via atomicMax on float bits ----------------

__global__ void k_pool_max(const __half* __restrict__ agg, const float* __restrict__ b,
                           const int* __restrict__ batch, unsigned* __restrict__ pooled, int n) {
    int idx = blockIdx.x * 256 + threadIdx.x;
    int node = idx >> 7;
    if (node >= n) return;
    int c = idx & 127;
    int g = batch[node];
    float v = __half2float(agg[(size_t)node * 128 + c]) + b[c];
    v = fmaxf(v, 0.f);
    atomicMax(&pooled[(size_t)g * 128 + c], __float_as_uint(v));
}

// ---------------- head: out[g] = pooled[g] @ Wl + bl ----------------

__global__ void k_final(const float* __restrict__ pooled, const float* __restrict__ Wl,
                        const float* __restrict__ bl, float* __restrict__ out) {
    int g = blockIdx.x;
    int t = threadIdx.x;  // 64 threads
    float p0 = pooled[(size_t)g * 128 + t];
    float p1 = pooled[(size_t)g * 128 + t + 64];
    float a0 = p0 * Wl[t * 2 + 0] + p1 * Wl[(t + 64) * 2 + 0];
    float a1 = p0 * Wl[t * 2 + 1] + p1 * Wl[(t + 64) * 2 + 1];
#pragma unroll
    for (int off = 32; off > 0; off >>= 1) {
        a0 += __shfl_down(a0, off);
        a1 += __shfl_down(a1, off);
    }
    if (t == 0) {
        out[g * 2 + 0] = a0 + bl[0];
        out[g * 2 + 1] = a1 + bl[1];
    }
}

// ---------------- launch ----------------

extern "C" void kernel_launch(void* const* d_in, const int* in_sizes, int n_in,
                              void* d_out, int out_size, void* d_ws, size_t ws_size,
                              hipStream_t stream) {
    const float* x  = (const float*)d_in[0];
    const int*   ei = (const int*)d_in[1];
    const int*   batch = (const int*)d_in[2];
    const float* W1 = (const float*)d_in[3];
    const float* b1 = (const float*)d_in[4];
    const float* W2 = (const float*)d_in[5];
    const float* b2 = (const float*)d_in[6];
    const float* W3 = (const float*)d_in[7];
    const float* b3 = (const float*)d_in[8];
    const float* Wl = (const float*)d_in[9];
    const float* bl = (const float*)d_in[10];
    float* out = (float*)d_out;

    const int N = N_NODES, E = N_EDGES;

    // workspace layout
    char* ws = (char*)d_ws;
    __half* bufA = (__half*)ws;                             // N*128 fp16 (hw)
    __half* bufB = bufA + (size_t)N * 128;                  // N*128 fp16 (agg)
    unsigned* pooled = (unsigned*)(bufB + (size_t)N * 128); // G*128
    float* dis  = (float*)(pooled + (size_t)N_GRAPHS * 128);
    float* dinv = dis + N;
    int*   rowptr = (int*)(dinv + N);                       // N+1
    int*   bkcnt  = rowptr + N + 2;                         // NBK
    int*   bkoff  = bkcnt + 256;                            // NBK+1
    int*   bcur   = bkoff + 256;                            // NBK
    int*   csrc   = bcur + 256;                             // E
    unsigned* pk  = (unsigned*)(csrc + E);                  // E (dead after passB)
    float* x8   = (float*)pk;                               // N*8 (aliases pk)
    float* aggx = x8 + (size_t)N * 8;                       // N*8 (aliases pk)

    // CSR build + norms (bucket hist -> scan -> radix passA/passB)
    hipMemsetAsync(bkcnt, 0, NBK * sizeof(int), stream);
    int nseg = (E + SEG - 1) / SEG;   // 196
    k_bhist<<<nseg, 256, 0, stream>>>(ei + E, E, bkcnt);
    k_bscan<<<1, 256, 0, stream>>>(bkcnt, bkoff, bcur, E);
    k_passA<<<nseg, 256, 0, stream>>>(ei, bcur, pk, E);
    k_passB<<<NBK, 256, 0, stream>>>(pk, bkoff, rowptr, dis, dinv, csrc, N, E);

    int ggrid = (N + 7) / 8;           // 2 nodes/wave, 4 waves/block
    int mfma_grid = (N + 127) / 128;   // 782

    // layer 1: aggregate raw x (7ch), then fused (aggx@W1 -> relu -> @W2)
    k_padx<<<(N * 8 + 255) / 256, 256, 0, stream>>>(x, x8, N);
    k_gather7<<<(N * 4 + 255) / 256, 256, 0, stream>>>(rowptr, csrc, dis, dinv,
                                                       (const float2*)x8, (float2*)aggx, N);
    k_l12<<<mfma_grid, 256, 0, stream>>>((const float2*)aggx, b1, W1, W2, bufA, N);

    // layer 2
    k_gather<<<ggrid, 256, 0, stream>>>(rowptr, csrc, dis, dinv,
                                        (const uint2*)bufA, (uint2*)bufB, N);
    k_gemm_mfma<<<mfma_grid, 256, 0, stream>>>(bufB, b2, W3, bufA, N);

    // layer 3: gather then standalone pool (atomics off the gather's critical path)
    k_gather<<<ggrid, 256, 0, stream>>>(rowptr, csrc, dis, dinv,
                                        (const uint2*)bufA, (uint2*)bufB, N);
    hipMemsetAsync(pooled, 0, (size_t)N_GRAPHS * 128 * sizeof(unsigned), stream);
    k_pool_max<<<(N * 128 + 255) / 256, 256, 0, stream>>>(bufB, b3, batch, pooled, N);

    // head
    k_final<<<N_GRAPHS, 64, 0, stream>>>((const float*)pooled, Wl, bl, out);
}

// Round 13
// 389.880 us; speedup vs baseline: 1.2402x; 1.0033x over previous
//
#include <hip/hip_runtime.h>
#include <hip/hip_fp16.h>

#define N_NODES 100000
#define N_EDGES 1600000
#define HID 128
#define N_GRAPHS 512
#define NBK 391      // ceil(N_NODES/256) dst-buckets (256-node buckets: 2x passB blocks vs R12)
#define SEG 4096     // edges per bhist/passA block (391 blocks)

typedef _Float16 f16x8 __attribute__((ext_vector_type(8)));
typedef float f32x4 __attribute__((ext_vector_type(4)));

// ---------------- CSR build: bucket histogram -> scan -> 2-pass radix ----------------
// R6-R8: random 4B stores/atomics to HBM-shared lines cost a 64B line
// writeback per op (8 non-coherent XCD L2s churn ownership). Fix: counts in
// LDS; every global write region block-exclusive & coalesced.

__global__ void k_bhist(const int* __restrict__ dst, int e, int* __restrict__ bkcnt) {
    __shared__ int l[NBK];
    int tid = threadIdx.x;
    for (int i = tid; i < NBK; i += 256) l[i] = 0;
    __syncthreads();
    int base = blockIdx.x * SEG;
    int m = min(SEG, e - base);
    for (int i = tid; i < m; i += 256) atomicAdd(&l[dst[base + i] >> 8], 1);
    __syncthreads();
    for (int b = tid; b < NBK; b += 256)
        if (l[b]) atomicAdd(&bkcnt[b], l[b]);
}

__global__ void k_bscan(const int* __restrict__ bkcnt, int* __restrict__ bkoff,
                        int* __restrict__ bcur, int e) {
    __shared__ int s[512];
    int t = threadIdx.x;
    int v = (t < NBK) ? bkcnt[t] : 0;
    s[t] = v;
    __syncthreads();
    for (int off = 1; off < 512; off <<= 1) {
        int u = (t >= off) ? s[t - off] : 0;
        __syncthreads();
        s[t] += u;
        __syncthreads();
    }
    int excl = s[t] - v;
    if (t < NBK) { bkoff[t] = excl; bcur[t] = excl; }
    if (t == NBK - 1) bkoff[NBK] = excl + v;   // == e
}

__launch_bounds__(256) __global__
void k_passA(const int* __restrict__ ei, int* __restrict__ bcur,
             unsigned* __restrict__ pk, int e) {
    __shared__ int lcnt[NBK];
    __shared__ int lbase[NBK];
    int tid = threadIdx.x;
    int base = blockIdx.x * SEG;
    for (int i = tid; i < NBK; i += 256) lcnt[i] = 0;
    __syncthreads();
    int m = min(SEG, e - base);
    for (int i = tid; i < m; i += 256) {
        int d = ei[N_EDGES + base + i];
        atomicAdd(&lcnt[d >> 8], 1);
    }
    __syncthreads();
    for (int b = tid; b < NBK; b += 256)
        lbase[b] = lcnt[b] ? atomicAdd(&bcur[b], lcnt[b]) : 0;
    __syncthreads();
    for (int i = tid; i < m; i += 256) {
        int s = ei[base + i];
        int d = ei[N_EDGES + base + i];
        int pos = atomicAdd(&lbase[d >> 8], 1);
        pk[pos] = ((unsigned)s << 8) | (unsigned)(d & 255);   // s<2^17: 25 bits
    }
}

__launch_bounds__(256) __global__
void k_passB(const unsigned* __restrict__ pk, const int* __restrict__ bkoff,
             int* __restrict__ rowptr, float* __restrict__ dis, float* __restrict__ dinv,
             int* __restrict__ csrc, int n, int e) {
    __shared__ int lcnt[256];
    __shared__ int sw[256];
    int b = blockIdx.x;
    int tid = threadIdx.x;
    int db0 = b * 256;
    int nd = min(256, n - db0);
    int pbeg = bkoff[b];
    int pend = bkoff[b + 1];
    lcnt[tid] = 0;
    __syncthreads();
    for (int i = pbeg + tid; i < pend; i += 256) atomicAdd(&lcnt[pk[i] & 255], 1);
    __syncthreads();
    if (tid < nd) {
        float d = (float)(lcnt[tid] + 1);   // +1 self-loop
        dis[db0 + tid] = rsqrtf(d);
        dinv[db0 + tid] = 1.0f / d;
    }
    int v = lcnt[tid];
    sw[tid] = v;
    __syncthreads();
    for (int off = 1; off < 256; off <<= 1) {
        int u = (tid >= off) ? sw[tid - off] : 0;
        __syncthreads();
        sw[tid] += u;
        __syncthreads();
    }
    int excl = sw[tid] - v;
    if (tid < nd) rowptr[db0 + tid] = pbeg + excl;
    if (db0 + nd == n && tid == 0) rowptr[n] = e;
    lcnt[tid] = pbeg + excl;   // global cursor
    __syncthreads();
    for (int i = pbeg + tid; i < pend; i += 256) {
        unsigned w = pk[i];
        int pos = atomicAdd(&lcnt[w & 255], 1);
        csrc[pos] = (int)(w >> 8);
    }
}

// ---------------- weight prep: W2,W3 -> fp16 transposed [n][k] (once) ----------------
// Kills per-GEMM-block fp32 fetch + scalar convert of W (R12: 64KB x 782 blocks).

__global__ void k_prepW(const float* __restrict__ W2, const float* __restrict__ W3,
                        __half* __restrict__ w2h, __half* __restrict__ w3h) {
    int i = blockIdx.x * 256 + threadIdx.x;
    if (i >= 128 * 128) return;
    int nn = i >> 7;
    int k = i & 127;
    w2h[i] = __float2half_rn(W2[k * 128 + nn]);
    w3h[i] = __float2half_rn(W3[k * 128 + nn]);
}

// ---------------- x padded to 8 channels (x8[i][7] = 0) ----------------

__global__ void k_padx(const float* __restrict__ x, float* __restrict__ x8, int n) {
    int i = blockIdx.x * 256 + threadIdx.x;
    if (i >= n * 8) return;
    int node = i >> 3;
    int k = i & 7;
    x8[i] = (k < 7) ? x[node * 7 + k] : 0.f;
}

// ---------------- layer-1 aggregation on RAW x (7ch, padded to 8) ----------------
// agg(x@W1) = agg(x)@W1: gather 32B/node-row (L2-resident) instead of 256B.
// Simple proven form: 4 threads/node, thread owns float2 pair qq.

__launch_bounds__(256) __global__
void k_gather7(const int* __restrict__ rowptr, const int* __restrict__ csrc,
               const float* __restrict__ dis, const float* __restrict__ dinv,
               const float2* __restrict__ x8v, float2* __restrict__ aggxv, int n) {
    int idx = blockIdx.x * 256 + threadIdx.x;
    int node = idx >> 2;
    if (node >= n) return;
    int qq = idx & 3;
    int beg = rowptr[node];
    int end = rowptr[node + 1];
    float dd = dis[node];
    float di = dinv[node];
    float2 acc = make_float2(0.f, 0.f);
    int j = beg;
    for (; j + 1 < end; j += 2) {
        int s0 = csrc[j];
        int s1 = csrc[j + 1];
        float w0 = dis[s0];
        float w1 = dis[s1];
        float2 v0 = x8v[(size_t)s0 * 4 + qq];
        float2 v1 = x8v[(size_t)s1 * 4 + qq];
        acc.x += v0.x * w0 + v1.x * w1;
        acc.y += v0.y * w0 + v1.y * w1;
    }
    if (j < end) {
        int s0 = csrc[j];
        float w0 = dis[s0];
        float2 v0 = x8v[(size_t)s0 * 4 + qq];
        acc.x += v0.x * w0;
        acc.y += v0.y * w0;
    }
    float2 ps = x8v[(size_t)node * 4 + qq];
    float2 r;
    r.x = ps.x * di + dd * acc.x;
    r.y = ps.y * di + dd * acc.y;
    aggxv[(size_t)node * 4 + qq] = r;
}

// ---------------- gather aggregation (fp16 rows, 128ch) ----------------
// agg[d] = dinv[d]*hw[d] + dis[d] * sum_s dis[s]*hw[s]
// 4 nodes/wave, 16 lanes x uint4 (16B) per row: one load instruction covers 4
// rows -> 2x rows in flight vs 2-node/uint2 form (latency-hiding A/B test).
// R11 lesson kept: no contended atomics fused here.

__device__ __forceinline__ void acc16(uint4 p, float w, float4& lo, float4& hi) {
    float2 t0 = __half22float2(*(__half2*)&p.x);
    float2 t1 = __half22float2(*(__half2*)&p.y);
    float2 t2 = __half22float2(*(__half2*)&p.z);
    float2 t3 = __half22float2(*(__half2*)&p.w);
    lo.x += t0.x * w; lo.y += t0.y * w; lo.z += t1.x * w; lo.w += t1.y * w;
    hi.x += t2.x * w; hi.y += t2.y * w; hi.z += t3.x * w; hi.w += t3.y * w;
}

__launch_bounds__(256) __global__
void k_gather(const int* __restrict__ rowptr, const int* __restrict__ csrc,
              const float* __restrict__ dis, const float* __restrict__ dinv,
              const uint4* __restrict__ hwv, uint4* __restrict__ aggv, int n) {
    int wid = blockIdx.x * 4 + (threadIdx.x >> 6);
    int lane = threadIdx.x & 63;
    int grp = lane >> 4;          // node subgroup 0..3
    int c = lane & 15;            // uint4 column (8 halves)
    int node = wid * 4 + grp;
    if (node >= n) return;        // N = 16 * grid exactly -> never mid-wave

    int beg = rowptr[node];
    int end = rowptr[node + 1];
    int deg = end - beg;
    float dd = dis[node];
    float di = dinv[node];

    // cooperative preload: 16 lanes cover up to 32 edges in two registers
    int s0i = 0, s1i = 0;
    float w0r = 0.f, w1r = 0.f;
    if (c < deg)      { s0i = csrc[beg + c];      w0r = dis[s0i]; }
    if (c + 16 < deg) { s1i = csrc[beg + 16 + c]; w1r = dis[s1i]; }

    int m = deg < 32 ? deg : 32;
    m = max(m, __shfl_xor(m, 16));
    m = max(m, __shfl_xor(m, 32));   // wave-uniform max over 4 groups
    int g16 = grp << 4;

    float4 alo = make_float4(0.f, 0.f, 0.f, 0.f);
    float4 ahi = make_float4(0.f, 0.f, 0.f, 0.f);

    int m0 = m < 16 ? m : 16;
    int j = 0;
    for (; j + 3 < m0; j += 4) {
        int a0 = __shfl(s0i, g16 + j);     float b0 = __shfl(w0r, g16 + j);
        int a1 = __shfl(s0i, g16 + j + 1); float b1 = __shfl(w0r, g16 + j + 1);
        int a2 = __shfl(s0i, g16 + j + 2); float b2 = __shfl(w0r, g16 + j + 2);
        int a3 = __shfl(s0i, g16 + j + 3); float b3 = __shfl(w0r, g16 + j + 3);
        uint4 p0 = hwv[(size_t)a0 * 16 + c];
        uint4 p1 = hwv[(size_t)a1 * 16 + c];
        uint4 p2 = hwv[(size_t)a2 * 16 + c];
        uint4 p3 = hwv[(size_t)a3 * 16 + c];
        acc16(p0, b0, alo, ahi); acc16(p1, b1, alo, ahi);
        acc16(p2, b2, alo, ahi); acc16(p3, b3, alo, ahi);
    }
    for (; j < m0; ++j) {
        int a0 = __shfl(s0i, g16 + j);
        float b0 = __shfl(w0r, g16 + j);
        uint4 p0 = hwv[(size_t)a0 * 16 + c];
        acc16(p0, b0, alo, ahi);
    }
    int j2 = 16;
    for (; j2 + 3 < m; j2 += 4) {
        int a0 = __shfl(s1i, g16 + j2 - 16); float b0 = __shfl(w1r, g16 + j2 - 16);
        int a1 = __shfl(s1i, g16 + j2 - 15); float b1 = __shfl(w1r, g16 + j2 - 15);
        int a2 = __shfl(s1i, g16 + j2 - 14); float b2 = __shfl(w1r, g16 + j2 - 14);
        int a3 = __shfl(s1i, g16 + j2 - 13); float b3 = __shfl(w1r, g16 + j2 - 13);
        uint4 p0 = hwv[(size_t)a0 * 16 + c];
        uint4 p1 = hwv[(size_t)a1 * 16 + c];
        uint4 p2 = hwv[(size_t)a2 * 16 + c];
        uint4 p3 = hwv[(size_t)a3 * 16 + c];
        acc16(p0, b0, alo, ahi); acc16(p1, b1, alo, ahi);
        acc16(p2, b2, alo, ahi); acc16(p3, b3, alo, ahi);
    }
    for (; j2 < m; ++j2) {
        int a0 = __shfl(s1i, g16 + j2 - 16);
        float b0 = __shfl(w1r, g16 + j2 - 16);
        uint4 p0 = hwv[(size_t)a0 * 16 + c];
        acc16(p0, b0, alo, ahi);
    }
    // rare tail (deg > 32): serial
    for (int jj = beg + 32; jj < end; ++jj) {
        int s = csrc[jj];
        float w = dis[s];
        uint4 p = hwv[(size_t)s * 16 + c];
        acc16(p, w, alo, ahi);
    }

    uint4 ps = hwv[(size_t)node * 16 + c];
    float2 q0 = __half22float2(*(__half2*)&ps.x);
    float2 q1 = __half22float2(*(__half2*)&ps.y);
    float2 q2 = __half22float2(*(__half2*)&ps.z);
    float2 q3 = __half22float2(*(__half2*)&ps.w);
    __half2 h0 = __floats2half2_rn(q0.x * di + dd * alo.x, q0.y * di + dd * alo.y);
    __half2 h1 = __floats2half2_rn(q1.x * di + dd * alo.z, q1.y * di + dd * alo.w);
    __half2 h2 = __floats2half2_rn(q2.x * di + dd * ahi.x, q2.y * di + dd * ahi.y);
    __half2 h3 = __floats2half2_rn(q3.x * di + dd * ahi.z, q3.y * di + dd * ahi.w);
    uint4 o;
    o.x = *(unsigned*)&h0; o.y = *(unsigned*)&h1;
    o.z = *(unsigned*)&h2; o.w = *(unsigned*)&h3;
    aggv[(size_t)node * 16 + c] = o;
}

// ---------------- fused layer1+2 GEMM: hw2 = relu(aggx@W1 + b1) @ W2 ----------------
// W2 pre-converted fp16 [n][k]; 4 x 64-row tiles per block (W staged once).

__device__ __forceinline__ int swz(int row, int kByte) {
    return row * 256 + (kByte ^ ((row & 7) << 4));
}

__device__ __forceinline__ void stageW(const __half* __restrict__ wh, _Float16* Wt, int tid) {
    for (int i = tid; i < 128 * 16; i += 256) {
        int nn = i >> 4;
        int kq = i & 15;
        uint4 v = ((const uint4*)wh)[i];
        *(uint4*)((char*)Wt + swz(nn, kq * 16)) = v;
    }
}

__launch_bounds__(256) __global__
void k_l12(const float2* __restrict__ aggxv, const float* __restrict__ b1,
           const float* __restrict__ W1, const __half* __restrict__ w2h,
           __half* __restrict__ hwout, int n) {
    __shared__ __align__(16) _Float16 Wt[128 * 128];  // 32 KB (W2^T swizzled)
    __shared__ __align__(16) _Float16 As[64 * 128];   // 16 KB
    int tid = threadIdx.x;
    stageW(w2h, Wt, tid);

    int rg = tid >> 5;         // 0..7: rows rg*8..rg*8+7
    int c4 = tid & 31;         // 4-channel group
    int col = c4 * 4;
    float4 w1k[7];
#pragma unroll
    for (int k = 0; k < 7; ++k) w1k[k] = *(const float4*)(W1 + k * 128 + col);
    float4 bb = *(const float4*)(b1 + col);

    int wv = tid >> 6;
    int lane = tid & 63;
    int lo16 = lane & 15;
    int hi4 = lane >> 4;

    for (int t = 0; t < 4; ++t) {
        if (t) __syncthreads();
#pragma unroll
        for (int rl = 0; rl < 8; ++rl) {
            int row = rg * 8 + rl;
            int grow = blockIdx.x * 256 + t * 64 + row;
            uint2 pk2 = make_uint2(0u, 0u);
            if (grow < n) {
                float2 a0 = aggxv[(size_t)grow * 4 + 0];
                float2 a1 = aggxv[(size_t)grow * 4 + 1];
                float2 a2 = aggxv[(size_t)grow * 4 + 2];
                float2 a3 = aggxv[(size_t)grow * 4 + 3];
                float4 acc = bb;
                acc.x += a0.x*w1k[0].x + a0.y*w1k[1].x + a1.x*w1k[2].x + a1.y*w1k[3].x
                       + a2.x*w1k[4].x + a2.y*w1k[5].x + a3.x*w1k[6].x;
                acc.y += a0.x*w1k[0].y + a0.y*w1k[1].y + a1.x*w1k[2].y + a1.y*w1k[3].y
                       + a2.x*w1k[4].y + a2.y*w1k[5].y + a3.x*w1k[6].y;
                acc.z += a0.x*w1k[0].z + a0.y*w1k[1].z + a1.x*w1k[2].z + a1.y*w1k[3].z
                       + a2.x*w1k[4].z + a2.y*w1k[5].z + a3.x*w1k[6].z;
                acc.w += a0.x*w1k[0].w + a0.y*w1k[1].w + a1.x*w1k[2].w + a1.y*w1k[3].w
                       + a2.x*w1k[4].w + a2.y*w1k[5].w + a3.x*w1k[6].w;
                __half2 h0 = __floats2half2_rn(fmaxf(acc.x, 0.f), fmaxf(acc.y, 0.f));
                __half2 h1 = __floats2half2_rn(fmaxf(acc.z, 0.f), fmaxf(acc.w, 0.f));
                pk2.x = *(unsigned*)&h0;
                pk2.y = *(unsigned*)&h1;
            }
            *(uint2*)((char*)As + swz(row, c4 * 8)) = pk2;
        }
        __syncthreads();

        f32x4 acc[8];
#pragma unroll
        for (int nt = 0; nt < 8; ++nt) acc[nt] = (f32x4){0.f, 0.f, 0.f, 0.f};
        const char* Ab = (const char*)As;
        const char* Bb = (const char*)Wt;
#pragma unroll
        for (int kt = 0; kt < 4; ++kt) {
            int kByte = kt * 64 + hi4 * 16;
            f16x8 af = *(const f16x8*)(Ab + swz(wv * 16 + lo16, kByte));
#pragma unroll
            for (int nt = 0; nt < 8; ++nt) {
                f16x8 bf = *(const f16x8*)(Bb + swz(nt * 16 + lo16, kByte));
                acc[nt] = __builtin_amdgcn_mfma_f32_16x16x32_f16(af, bf, acc[nt], 0, 0, 0);
            }
        }
        int rbase = blockIdx.x * 256 + t * 64 + wv * 16 + hi4 * 4;
#pragma unroll
        for (int nt = 0; nt < 8; ++nt) {
#pragma unroll
            for (int r = 0; r < 4; ++r) {
                int node = rbase + r;
                if (node < n)
                    hwout[(size_t)node * 128 + nt * 16 + lo16] = __float2half_rn(acc[nt][r]);
            }
        }
    }
}

// ---------------- MFMA GEMM: hwout = relu(aggin + b) @ W  (fp16 in/out) ----------------
// W pre-converted fp16 [n][k]; 4 x 64-row tiles per block.

__launch_bounds__(256) __global__
void k_gemm_mfma(const __half* __restrict__ aggin, const float* __restrict__ b,
                 const __half* __restrict__ wh, __half* __restrict__ hwout, int n) {
    __shared__ __align__(16) _Float16 Wt[128 * 128];  // 32 KB
    __shared__ __align__(16) _Float16 As[64 * 128];   // 16 KB
    int tid = threadIdx.x;
    stageW(wh, Wt, tid);

    int row = tid >> 2;
    int q = tid & 3;
    int wv = tid >> 6;
    int lane = tid & 63;
    int lo16 = lane & 15;
    int hi4 = lane >> 4;

    for (int t = 0; t < 4; ++t) {
        if (t) __syncthreads();
        int grow = blockIdx.x * 256 + t * 64 + row;
#pragma unroll
        for (int j = 0; j < 4; ++j) {
            int c0 = q * 32 + j * 8;
            uint4 pk = make_uint4(0u, 0u, 0u, 0u);
            if (grow < n) {
                uint4 p = *(const uint4*)(aggin + (size_t)grow * 128 + c0);
                float4 bA = *(const float4*)(b + c0);
                float4 bB = *(const float4*)(b + c0 + 4);
                float2 t0 = __half22float2(*(const __half2*)&p.x);
                float2 t1 = __half22float2(*(const __half2*)&p.y);
                float2 t2 = __half22float2(*(const __half2*)&p.z);
                float2 t3 = __half22float2(*(const __half2*)&p.w);
                __half2 h0 = __floats2half2_rn(fmaxf(t0.x + bA.x, 0.f), fmaxf(t0.y + bA.y, 0.f));
                __half2 h1 = __floats2half2_rn(fmaxf(t1.x + bA.z, 0.f), fmaxf(t1.y + bA.w, 0.f));
                __half2 h2 = __floats2half2_rn(fmaxf(t2.x + bB.x, 0.f), fmaxf(t2.y + bB.y, 0.f));
                __half2 h3 = __floats2half2_rn(fmaxf(t3.x + bB.z, 0.f), fmaxf(t3.y + bB.w, 0.f));
                pk.x = *(unsigned*)&h0; pk.y = *(unsigned*)&h1;
                pk.z = *(unsigned*)&h2; pk.w = *(unsigned*)&h3;
            }
            *(uint4*)((char*)As + swz(row, c0 * 2)) = pk;
        }
        __syncthreads();

        f32x4 acc[8];
#pragma unroll
        for (int nt = 0; nt < 8; ++nt) acc[nt] = (f32x4){0.f, 0.f, 0.f, 0.f};

        const char* Ab = (const char*)As;
        const char* Bb = (const char*)Wt;
#pragma unroll
        for (int kt = 0; kt < 4; ++kt) {
            int kByte = kt * 64 + hi4 * 16;
            f16x8 af = *(const f16x8*)(Ab + swz(wv * 16 + lo16, kByte));
#pragma unroll
            for (int nt = 0; nt < 8; ++nt) {
                f16x8 bf = *(const f16x8*)(Bb + swz(nt * 16 + lo16, kByte));
                acc[nt] = __builtin_amdgcn_mfma_f32_16x16x32_f16(af, bf, acc[nt], 0, 0, 0);
            }
        }

        int rbase = blockIdx.x * 256 + t * 64 + wv * 16 + hi4 * 4;
#pragma unroll
        for (int nt = 0; nt < 8; ++nt) {
#pragma unroll
            for (int r = 0; r < 4; ++r) {
                int node = rbase + r;
                if (node < n)
                    hwout[(size_t)node * 128 + nt * 16 + lo16] = __float2half_rn(acc[nt][r]);
            }
        }
    }
}

// ---------------- pooling: segment_max(relu(agg+b)) via atomicMax on float bits ----------------

__global__ void k_pool_max(const __half* __restrict__ agg, const float* __restrict__ b,
                           const int* __restrict__ batch, unsigned* __restrict__ pooled, int n) {
    int idx = blockIdx.x * 256 + threadIdx.x;
    int node = idx >> 7;
    if (node >= n) return;
    int c = idx & 127;
    int g = batch[node];
    float v = __half2float(agg[(size_t)node * 128 + c]) + b[c];
    v = fmaxf(v, 0.f);
    atomicMax(&pooled[(size_t)g * 128 + c], __float_as_uint(v));
}

// ---------------- head: out[g] = pooled[g] @ Wl + bl ----------------

__global__ void k_final(const float* __restrict__ pooled, const float* __restrict__ Wl,
                        const float* __restrict__ bl, float* __restrict__ out) {
    int g = blockIdx.x;
    int t = threadIdx.x;  // 64 threads
    float p0 = pooled[(size_t)g * 128 + t];
    float p1 = pooled[(size_t)g * 128 + t + 64];
    float a0 = p0 * Wl[t * 2 + 0] + p1 * Wl[(t + 64) * 2 + 0];
    float a1 = p0 * Wl[t * 2 + 1] + p1 * Wl[(t + 64) * 2 + 1];
#pragma unroll
    for (int off = 32; off > 0; off >>= 1) {
        a0 += __shfl_down(a0, off);
        a1 += __shfl_down(a1, off);
    }
    if (t == 0) {
        out[g * 2 + 0] = a0 + bl[0];
        out[g * 2 + 1] = a1 + bl[1];
    }
}

// ---------------- launch ----------------

extern "C" void kernel_launch(void* const* d_in, const int* in_sizes, int n_in,
                              void* d_out, int out_size, void* d_ws, size_t ws_size,
                              hipStream_t stream) {
    const float* x  = (const float*)d_in[0];
    const int*   ei = (const int*)d_in[1];
    const int*   batch = (const int*)d_in[2];
    const float* W1 = (const float*)d_in[3];
    const float* b1 = (const float*)d_in[4];
    const float* W2 = (const float*)d_in[5];
    const float* b2 = (const float*)d_in[6];
    const float* W3 = (const float*)d_in[7];
    const float* b3 = (const float*)d_in[8];
    const float* Wl = (const float*)d_in[9];
    const float* bl = (const float*)d_in[10];
    float* out = (float*)d_out;

    const int N = N_NODES, E = N_EDGES;

    // workspace layout
    char* ws = (char*)d_ws;
    __half* bufA = (__half*)ws;                             // N*128 fp16 (hw)
    __half* bufB = bufA + (size_t)N * 128;                  // N*128 fp16 (agg)
    unsigned* pooled = (unsigned*)(bufB + (size_t)N * 128); // G*128
    float* dis  = (float*)(pooled + (size_t)N_GRAPHS * 128);
    float* dinv = dis + N;
    int*   rowptr = (int*)(dinv + N);                       // N+1
    int*   bkcnt  = rowptr + N + 2;                         // NBK (<=512)
    int*   bkoff  = bkcnt + 512;                            // NBK+1
    int*   bcur   = bkoff + 512;                            // NBK
    int*   csrc   = bcur + 512;                             // E
    unsigned* pk  = (unsigned*)(csrc + E);                  // E (dead after passB)
    float* x8   = (float*)pk;                               // N*8 (aliases pk)
    float* aggx = x8 + (size_t)N * 8;                       // N*8 (aliases pk; 6.4MB total = pk size)
    __half* w2h = (__half*)(pk + E);                        // 128*128 fp16
    __half* w3h = w2h + 128 * 128;                          // 128*128 fp16

    // CSR build + norms (bucket hist -> scan -> radix passA/passB), 256-node buckets
    hipMemsetAsync(bkcnt, 0, NBK * sizeof(int), stream);
    int nseg = (E + SEG - 1) / SEG;   // 391
    k_bhist<<<nseg, 256, 0, stream>>>(ei + E, E, bkcnt);
    k_bscan<<<1, 512, 0, stream>>>(bkcnt, bkoff, bcur, E);
    k_passA<<<nseg, 256, 0, stream>>>(ei, bcur, pk, E);
    k_passB<<<NBK, 256, 0, stream>>>(pk, bkoff, rowptr, dis, dinv, csrc, N, E);

    // weight prep (independent of CSR; overlaps nothing but is tiny)
    k_prepW<<<64, 256, 0, stream>>>(W2, W3, w2h, w3h);

    int ggrid = (N + 15) / 16;         // 4 nodes/wave, 4 waves/block = 6250
    int mfma_grid = (N + 255) / 256;   // 391

    // layer 1: aggregate raw x (7ch), then fused (aggx@W1 -> relu -> @W2)
    k_padx<<<(N * 8 + 255) / 256, 256, 0, stream>>>(x, x8, N);
    k_gather7<<<(N * 4 + 255) / 256, 256, 0, stream>>>(rowptr, csrc, dis, dinv,
                                                       (const float2*)x8, (float2*)aggx, N);
    k_l12<<<mfma_grid, 256, 0, stream>>>((const float2*)aggx, b1, W1, w2h, bufA, N);

    // layer 2
    k_gather<<<ggrid, 256, 0, stream>>>(rowptr, csrc, dis, dinv,
                                        (const uint4*)bufA, (uint4*)bufB, N);
    k_gemm_mfma<<<mfma_grid, 256, 0, stream>>>(bufB, b2, w3h, bufA, N);

    // layer 3: gather then standalone pool (atomics off the gather's critical path)
    k_gather<<<ggrid, 256, 0, stream>>>(rowptr, csrc, dis, dinv,
                                        (const uint4*)bufA, (uint4*)bufB, N);
    hipMemsetAsync(pooled, 0, (size_t)N_GRAPHS * 128 * sizeof(unsigned), stream);
    k_pool_max<<<(N * 128 + 255) / 256, 256, 0, stream>>>(bufB, b3, batch, pooled, N);

    // head
    k_final<<<N_GRAPHS, 64, 0, stream>>>((const float*)pooled, Wl, bl, out);
}

// Round 15
// 376.239 us; speedup vs baseline: 1.2851x; 1.0363x over previous
//
#include <hip/hip_runtime.h>
#include <hip/hip_fp16.h>

#define N_NODES 100000
#define N_EDGES 1600000
#define HID 128
#define N_GRAPHS 512
#define NBK 391      // ceil(N_NODES/256) dst-buckets
#define SEG 4096     // edges per bhist/passA block (391 blocks)

typedef _Float16 f16x8 __attribute__((ext_vector_type(8)));
typedef float f32x4 __attribute__((ext_vector_type(4)));

// ---------------- CSR build: bucket histogram -> scan -> 2-pass radix ----------------
// R6-R8: random 4B stores/atomics to HBM-shared lines cost a 64B line
// writeback per op (8 non-coherent XCD L2s churn ownership). Fix: counts in
// LDS; every global write region block-exclusive & coalesced.

__global__ void k_bhist(const int* __restrict__ dst, int e, int* __restrict__ bkcnt) {
    __shared__ int l[NBK];
    int tid = threadIdx.x;
    for (int i = tid; i < NBK; i += 256) l[i] = 0;
    __syncthreads();
    int base = blockIdx.x * SEG;
    int m = min(SEG, e - base);
    for (int i = tid; i < m; i += 256) atomicAdd(&l[dst[base + i] >> 8], 1);
    __syncthreads();
    for (int b = tid; b < NBK; b += 256)
        if (l[b]) atomicAdd(&bkcnt[b], l[b]);
}

__global__ void k_bscan(const int* __restrict__ bkcnt, int* __restrict__ bkoff,
                        int* __restrict__ bcur, int e) {
    __shared__ int s[512];
    int t = threadIdx.x;
    int v = (t < NBK) ? bkcnt[t] : 0;
    s[t] = v;
    __syncthreads();
    for (int off = 1; off < 512; off <<= 1) {
        int u = (t >= off) ? s[t - off] : 0;
        __syncthreads();
        s[t] += u;
        __syncthreads();
    }
    int excl = s[t] - v;
    if (t < NBK) { bkoff[t] = excl; bcur[t] = excl; }
    if (t == NBK - 1) bkoff[NBK] = excl + v;   // == e
}

__launch_bounds__(256) __global__
void k_passA(const int* __restrict__ ei, int* __restrict__ bcur,
             unsigned* __restrict__ pk, int e) {
    __shared__ int lcnt[NBK];
    __shared__ int lbase[NBK];
    int tid = threadIdx.x;
    int base = blockIdx.x * SEG;
    for (int i = tid; i < NBK; i += 256) lcnt[i] = 0;
    __syncthreads();
    int m = min(SEG, e - base);
    for (int i = tid; i < m; i += 256) {
        int d = ei[N_EDGES + base + i];
        atomicAdd(&lcnt[d >> 8], 1);
    }
    __syncthreads();
    for (int b = tid; b < NBK; b += 256)
        lbase[b] = lcnt[b] ? atomicAdd(&bcur[b], lcnt[b]) : 0;
    __syncthreads();
    for (int i = tid; i < m; i += 256) {
        int s = ei[base + i];
        int d = ei[N_EDGES + base + i];
        int pos = atomicAdd(&lbase[d >> 8], 1);
        pk[pos] = ((unsigned)s << 8) | (unsigned)(d & 255);   // s<2^17: 25 bits
    }
}

__launch_bounds__(256) __global__
void k_passB(const unsigned* __restrict__ pk, const int* __restrict__ bkoff,
             int* __restrict__ rowptr, float* __restrict__ dis, float* __restrict__ dinv,
             int* __restrict__ csrc, int n, int e) {
    __shared__ int lcnt[256];
    __shared__ int sw[256];
    int b = blockIdx.x;
    int tid = threadIdx.x;
    int db0 = b * 256;
    int nd = min(256, n - db0);
    int pbeg = bkoff[b];
    int pend = bkoff[b + 1];
    lcnt[tid] = 0;
    __syncthreads();
    for (int i = pbeg + tid; i < pend; i += 256) atomicAdd(&lcnt[pk[i] & 255], 1);
    __syncthreads();
    if (tid < nd) {
        float d = (float)(lcnt[tid] + 1);   // +1 self-loop
        dis[db0 + tid] = rsqrtf(d);
        dinv[db0 + tid] = 1.0f / d;
    }
    int v = lcnt[tid];
    sw[tid] = v;
    __syncthreads();
    for (int off = 1; off < 256; off <<= 1) {
        int u = (tid >= off) ? sw[tid - off] : 0;
        __syncthreads();
        sw[tid] += u;
        __syncthreads();
    }
    int excl = sw[tid] - v;
    if (tid < nd) rowptr[db0 + tid] = pbeg + excl;
    if (db0 + nd == n && tid == 0) rowptr[n] = e;
    lcnt[tid] = pbeg + excl;   // global cursor
    __syncthreads();
    for (int i = pbeg + tid; i < pend; i += 256) {
        unsigned w = pk[i];
        int pos = atomicAdd(&lcnt[w & 255], 1);
        csrc[pos] = (int)(w >> 8);
    }
}

// ---------------- misc: prepW + zero(bkcnt) + zero(pooled), one launch ----------------
// NOTE (R14 lesson): padx must NOT be here — x8 aliases pk, which is live
// until passB completes. padx runs after passB (R13-proven ordering).

__global__ void k_misc(const float* __restrict__ W2, const float* __restrict__ W3,
                       __half* __restrict__ w2h, __half* __restrict__ w3h,
                       int* __restrict__ bkcnt, unsigned* __restrict__ pooled) {
    int i = blockIdx.x * 256 + threadIdx.x;
    if (i < 128 * 128) {
        int nn = i >> 7;
        int k = i & 127;
        w2h[i] = __float2half_rn(W2[k * 128 + nn]);
        w3h[i] = __float2half_rn(W3[k * 128 + nn]);
    }
    if (i < NBK) bkcnt[i] = 0;
    if (i < N_GRAPHS * 128) pooled[i] = 0u;
}

// ---------------- x padded to 8 channels (x8[i][7] = 0) ----------------

__global__ void k_padx(const float* __restrict__ x, float* __restrict__ x8, int n) {
    int i = blockIdx.x * 256 + threadIdx.x;
    if (i >= n * 8) return;
    int node = i >> 3;
    int k = i & 7;
    x8[i] = (k < 7) ? x[node * 7 + k] : 0.f;
}

// ---------------- layer-1 aggregation on RAW x (7ch, padded to 8) ----------------
// agg(x@W1) = agg(x)@W1: gather 32B/node-row (L2-resident) instead of 256B.

__launch_bounds__(256) __global__
void k_gather7(const int* __restrict__ rowptr, const int* __restrict__ csrc,
               const float* __restrict__ dis, const float* __restrict__ dinv,
               const float2* __restrict__ x8v, float2* __restrict__ aggxv, int n) {
    int idx = blockIdx.x * 256 + threadIdx.x;
    int node = idx >> 2;
    if (node >= n) return;
    int qq = idx & 3;
    int beg = rowptr[node];
    int end = rowptr[node + 1];
    float dd = dis[node];
    float di = dinv[node];
    float2 acc = make_float2(0.f, 0.f);
    int j = beg;
    for (; j + 1 < end; j += 2) {
        int s0 = csrc[j];
        int s1 = csrc[j + 1];
        float w0 = dis[s0];
        float w1 = dis[s1];
        float2 v0 = x8v[(size_t)s0 * 4 + qq];
        float2 v1 = x8v[(size_t)s1 * 4 + qq];
        acc.x += v0.x * w0 + v1.x * w1;
        acc.y += v0.y * w0 + v1.y * w1;
    }
    if (j < end) {
        int s0 = csrc[j];
        float w0 = dis[s0];
        float2 v0 = x8v[(size_t)s0 * 4 + qq];
        acc.x += v0.x * w0;
        acc.y += v0.y * w0;
    }
    float2 ps = x8v[(size_t)node * 4 + qq];
    float2 r;
    r.x = ps.x * di + dd * acc.x;
    r.y = ps.y * di + dd * acc.y;
    aggxv[(size_t)node * 4 + qq] = r;
}

// ---------------- gather aggregation (fp16 rows, 128ch) ----------------
// agg[d] = dinv[d]*hw[d] + dis[d] * sum_s dis[s]*hw[s]
// At the random-access memory bound (R13 A/B null) — structure frozen.

__device__ __forceinline__ void acc16(uint4 p, float w, float4& lo, float4& hi) {
    float2 t0 = __half22float2(*(__half2*)&p.x);
    float2 t1 = __half22float2(*(__half2*)&p.y);
    float2 t2 = __half22float2(*(__half2*)&p.z);
    float2 t3 = __half22float2(*(__half2*)&p.w);
    lo.x += t0.x * w; lo.y += t0.y * w; lo.z += t1.x * w; lo.w += t1.y * w;
    hi.x += t2.x * w; hi.y += t2.y * w; hi.z += t3.x * w; hi.w += t3.y * w;
}

__launch_bounds__(256) __global__
void k_gather(const int* __restrict__ rowptr, const int* __restrict__ csrc,
              const float* __restrict__ dis, const float* __restrict__ dinv,
              const uint4* __restrict__ hwv, uint4* __restrict__ aggv, int n) {
    int wid = blockIdx.x * 4 + (threadIdx.x >> 6);
    int lane = threadIdx.x & 63;
    int grp = lane >> 4;
    int c = lane & 15;
    int node = wid * 4 + grp;
    if (node >= n) return;

    int beg = rowptr[node];
    int end = rowptr[node + 1];
    int deg = end - beg;
    float dd = dis[node];
    float di = dinv[node];

    int s0i = 0, s1i = 0;
    float w0r = 0.f, w1r = 0.f;
    if (c < deg)      { s0i = csrc[beg + c];      w0r = dis[s0i]; }
    if (c + 16 < deg) { s1i = csrc[beg + 16 + c]; w1r = dis[s1i]; }

    int m = deg < 32 ? deg : 32;
    m = max(m, __shfl_xor(m, 16));
    m = max(m, __shfl_xor(m, 32));
    int g16 = grp << 4;

    float4 alo = make_float4(0.f, 0.f, 0.f, 0.f);
    float4 ahi = make_float4(0.f, 0.f, 0.f, 0.f);

    int m0 = m < 16 ? m : 16;
    int j = 0;
    for (; j + 3 < m0; j += 4) {
        int a0 = __shfl(s0i, g16 + j);     float b0 = __shfl(w0r, g16 + j);
        int a1 = __shfl(s0i, g16 + j + 1); float b1 = __shfl(w0r, g16 + j + 1);
        int a2 = __shfl(s0i, g16 + j + 2); float b2 = __shfl(w0r, g16 + j + 2);
        int a3 = __shfl(s0i, g16 + j + 3); float b3 = __shfl(w0r, g16 + j + 3);
        uint4 p0 = hwv[(size_t)a0 * 16 + c];
        uint4 p1 = hwv[(size_t)a1 * 16 + c];
        uint4 p2 = hwv[(size_t)a2 * 16 + c];
        uint4 p3 = hwv[(size_t)a3 * 16 + c];
        acc16(p0, b0, alo, ahi); acc16(p1, b1, alo, ahi);
        acc16(p2, b2, alo, ahi); acc16(p3, b3, alo, ahi);
    }
    for (; j < m0; ++j) {
        int a0 = __shfl(s0i, g16 + j);
        float b0 = __shfl(w0r, g16 + j);
        uint4 p0 = hwv[(size_t)a0 * 16 + c];
        acc16(p0, b0, alo, ahi);
    }
    int j2 = 16;
    for (; j2 + 3 < m; j2 += 4) {
        int a0 = __shfl(s1i, g16 + j2 - 16); float b0 = __shfl(w1r, g16 + j2 - 16);
        int a1 = __shfl(s1i, g16 + j2 - 15); float b1 = __shfl(w1r, g16 + j2 - 15);
        int a2 = __shfl(s1i, g16 + j2 - 14); float b2 = __shfl(w1r, g16 + j2 - 14);
        int a3 = __shfl(s1i, g16 + j2 - 13); float b3 = __shfl(w1r, g16 + j2 - 13);
        uint4 p0 = hwv[(size_t)a0 * 16 + c];
        uint4 p1 = hwv[(size_t)a1 * 16 + c];
        uint4 p2 = hwv[(size_t)a2 * 16 + c];
        uint4 p3 = hwv[(size_t)a3 * 16 + c];
        acc16(p0, b0, alo, ahi); acc16(p1, b1, alo, ahi);
        acc16(p2, b2, alo, ahi); acc16(p3, b3, alo, ahi);
    }
    for (; j2 < m; ++j2) {
        int a0 = __shfl(s1i, g16 + j2 - 16);
        float b0 = __shfl(w1r, g16 + j2 - 16);
        uint4 p0 = hwv[(size_t)a0 * 16 + c];
        acc16(p0, b0, alo, ahi);
    }
    for (int jj = beg + 32; jj < end; ++jj) {
        int s = csrc[jj];
        float w = dis[s];
        uint4 p = hwv[(size_t)s * 16 + c];
        acc16(p, w, alo, ahi);
    }

    uint4 ps = hwv[(size_t)node * 16 + c];
    float2 q0 = __half22float2(*(__half2*)&ps.x);
    float2 q1 = __half22float2(*(__half2*)&ps.y);
    float2 q2 = __half22float2(*(__half2*)&ps.z);
    float2 q3 = __half22float2(*(__half2*)&ps.w);
    __half2 h0 = __floats2half2_rn(q0.x * di + dd * alo.x, q0.y * di + dd * alo.y);
    __half2 h1 = __floats2half2_rn(q1.x * di + dd * alo.z, q1.y * di + dd * alo.w);
    __half2 h2 = __floats2half2_rn(q2.x * di + dd * ahi.x, q2.y * di + dd * ahi.y);
    __half2 h3 = __floats2half2_rn(q3.x * di + dd * ahi.z, q3.y * di + dd * ahi.w);
    uint4 o;
    o.x = *(unsigned*)&h0; o.y = *(unsigned*)&h1;
    o.z = *(unsigned*)&h2; o.w = *(unsigned*)&h3;
    aggv[(size_t)node * 16 + c] = o;
}

// ---------------- GEMMs: 1 x 64-row tile per block (grid 1563, 3 blocks/CU) ----------------

__device__ __forceinline__ int swz(int row, int kByte) {
    return row * 256 + (kByte ^ ((row & 7) << 4));
}

__device__ __forceinline__ void stageW(const __half* __restrict__ wh, _Float16* Wt, int tid) {
    for (int i = tid; i < 128 * 16; i += 256) {
        int nn = i >> 4;
        int kq = i & 15;
        uint4 v = ((const uint4*)wh)[i];
        *(uint4*)((char*)Wt + swz(nn, kq * 16)) = v;
    }
}

__launch_bounds__(256) __global__
void k_l12(const float2* __restrict__ aggxv, const float* __restrict__ b1,
           const float* __restrict__ W1, const __half* __restrict__ w2h,
           __half* __restrict__ hwout, int n) {
    __shared__ __align__(16) _Float16 Wt[128 * 128];  // 32 KB (W2^T swizzled)
    __shared__ __align__(16) _Float16 As[64 * 128];   // 16 KB
    int tid = threadIdx.x;
    stageW(w2h, Wt, tid);

    int rg = tid >> 5;         // 0..7: rows rg*8..rg*8+7
    int c4 = tid & 31;         // 4-channel group
    int col = c4 * 4;
    float4 w1k[7];
#pragma unroll
    for (int k = 0; k < 7; ++k) w1k[k] = *(const float4*)(W1 + k * 128 + col);
    float4 bb = *(const float4*)(b1 + col);

#pragma unroll
    for (int rl = 0; rl < 8; ++rl) {
        int row = rg * 8 + rl;
        int grow = blockIdx.x * 64 + row;
        uint2 pk2 = make_uint2(0u, 0u);
        if (grow < n) {
            float2 a0 = aggxv[(size_t)grow * 4 + 0];
            float2 a1 = aggxv[(size_t)grow * 4 + 1];
            float2 a2 = aggxv[(size_t)grow * 4 + 2];
            float2 a3 = aggxv[(size_t)grow * 4 + 3];
            float4 acc = bb;
            acc.x += a0.x*w1k[0].x + a0.y*w1k[1].x + a1.x*w1k[2].x + a1.y*w1k[3].x
                   + a2.x*w1k[4].x + a2.y*w1k[5].x + a3.x*w1k[6].x;
            acc.y += a0.x*w1k[0].y + a0.y*w1k[1].y + a1.x*w1k[2].y + a1.y*w1k[3].y
                   + a2.x*w1k[4].y + a2.y*w1k[5].y + a3.x*w1k[6].y;
            acc.z += a0.x*w1k[0].z + a0.y*w1k[1].z + a1.x*w1k[2].z + a1.y*w1k[3].z
                   + a2.x*w1k[4].z + a2.y*w1k[5].z + a3.x*w1k[6].z;
            acc.w += a0.x*w1k[0].w + a0.y*w1k[1].w + a1.x*w1k[2].w + a1.y*w1k[3].w
                   + a2.x*w1k[4].w + a2.y*w1k[5].w + a3.x*w1k[6].w;
            __half2 h0 = __floats2half2_rn(fmaxf(acc.x, 0.f), fmaxf(acc.y, 0.f));
            __half2 h1 = __floats2half2_rn(fmaxf(acc.z, 0.f), fmaxf(acc.w, 0.f));
            pk2.x = *(unsigned*)&h0;
            pk2.y = *(unsigned*)&h1;
        }
        *(uint2*)((char*)As + swz(row, c4 * 8)) = pk2;
    }
    __syncthreads();

    int wv = tid >> 6;
    int lane = tid & 63;
    int lo16 = lane & 15;
    int hi4 = lane >> 4;

    f32x4 acc[8];
#pragma unroll
    for (int nt = 0; nt < 8; ++nt) acc[nt] = (f32x4){0.f, 0.f, 0.f, 0.f};
    const char* Ab = (const char*)As;
    const char* Bb = (const char*)Wt;
#pragma unroll
    for (int kt = 0; kt < 4; ++kt) {
        int kByte = kt * 64 + hi4 * 16;
        f16x8 af = *(const f16x8*)(Ab + swz(wv * 16 + lo16, kByte));
#pragma unroll
        for (int nt = 0; nt < 8; ++nt) {
            f16x8 bf = *(const f16x8*)(Bb + swz(nt * 16 + lo16, kByte));
            acc[nt] = __builtin_amdgcn_mfma_f32_16x16x32_f16(af, bf, acc[nt], 0, 0, 0);
        }
    }
    int rbase = blockIdx.x * 64 + wv * 16 + hi4 * 4;
#pragma unroll
    for (int nt = 0; nt < 8; ++nt) {
#pragma unroll
        for (int r = 0; r < 4; ++r) {
            int node = rbase + r;
            if (node < n)
                hwout[(size_t)node * 128 + nt * 16 + lo16] = __float2half_rn(acc[nt][r]);
        }
    }
}

__launch_bounds__(256) __global__
void k_gemm_mfma(const __half* __restrict__ aggin, const float* __restrict__ b,
                 const __half* __restrict__ wh, __half* __restrict__ hwout, int n) {
    __shared__ __align__(16) _Float16 Wt[128 * 128];  // 32 KB
    __shared__ __align__(16) _Float16 As[64 * 128];   // 16 KB
    int tid = threadIdx.x;
    stageW(wh, Wt, tid);

    int row = tid >> 2;
    int q = tid & 3;
    int grow = blockIdx.x * 64 + row;
#pragma unroll
    for (int j = 0; j < 4; ++j) {
        int c0 = q * 32 + j * 8;
        uint4 pk = make_uint4(0u, 0u, 0u, 0u);
        if (grow < n) {
            uint4 p = *(const uint4*)(aggin + (size_t)grow * 128 + c0);
            float4 bA = *(const float4*)(b + c0);
            float4 bB = *(const float4*)(b + c0 + 4);
            float2 t0 = __half22float2(*(const __half2*)&p.x);
            float2 t1 = __half22float2(*(const __half2*)&p.y);
            float2 t2 = __half22float2(*(const __half2*)&p.z);
            float2 t3 = __half22float2(*(const __half2*)&p.w);
            __half2 h0 = __floats2half2_rn(fmaxf(t0.x + bA.x, 0.f), fmaxf(t0.y + bA.y, 0.f));
            __half2 h1 = __floats2half2_rn(fmaxf(t1.x + bA.z, 0.f), fmaxf(t1.y + bA.w, 0.f));
            __half2 h2 = __floats2half2_rn(fmaxf(t2.x + bB.x, 0.f), fmaxf(t2.y + bB.y, 0.f));
            __half2 h3 = __floats2half2_rn(fmaxf(t3.x + bB.z, 0.f), fmaxf(t3.y + bB.w, 0.f));
            pk.x = *(unsigned*)&h0; pk.y = *(unsigned*)&h1;
            pk.z = *(unsigned*)&h2; pk.w = *(unsigned*)&h3;
        }
        *(uint4*)((char*)As + swz(row, c0 * 2)) = pk;
    }
    __syncthreads();

    int wv = tid >> 6;
    int lane = tid & 63;
    int lo16 = lane & 15;
    int hi4 = lane >> 4;

    f32x4 acc[8];
#pragma unroll
    for (int nt = 0; nt < 8; ++nt) acc[nt] = (f32x4){0.f, 0.f, 0.f, 0.f};

    const char* Ab = (const char*)As;
    const char* Bb = (const char*)Wt;
#pragma unroll
    for (int kt = 0; kt < 4; ++kt) {
        int kByte = kt * 64 + hi4 * 16;
        f16x8 af = *(const f16x8*)(Ab + swz(wv * 16 + lo16, kByte));
#pragma unroll
        for (int nt = 0; nt < 8; ++nt) {
            f16x8 bf = *(const f16x8*)(Bb + swz(nt * 16 + lo16, kByte));
            acc[nt] = __builtin_amdgcn_mfma_f32_16x16x32_f16(af, bf, acc[nt], 0, 0, 0);
        }
    }

    int rbase = blockIdx.x * 64 + wv * 16 + hi4 * 4;
#pragma unroll
    for (int nt = 0; nt < 8; ++nt) {
#pragma unroll
        for (int r = 0; r < 4; ++r) {
            int node = rbase + r;
            if (node < n)
                hwout[(size_t)node * 128 + nt * 16 + lo16] = __float2half_rn(acc[nt][r]);
        }
    }
}

// ---------------- pooling: segment_max(relu(agg+b)) via atomicMax on float bits ----------------

__global__ void k_pool_max(const __half* __restrict__ agg, const float* __restrict__ b,
                           const int* __restrict__ batch, unsigned* __restrict__ pooled, int n) {
    int idx = blockIdx.x * 256 + threadIdx.x;
    int node = idx >> 7;
    if (node >= n) return;
    int c = idx & 127;
    int g = batch[node];
    float v = __half2float(agg[(size_t)node * 128 + c]) + b[c];
    v = fmaxf(v, 0.f);
    atomicMax(&pooled[(size_t)g * 128 + c], __float_as_uint(v));
}

// ---------------- head: out[g] = pooled[g] @ Wl + bl ----------------

__global__ void k_final(const float* __restrict__ pooled, const float* __restrict__ Wl,
                        const float* __restrict__ bl, float* __restrict__ out) {
    int g = blockIdx.x;
    int t = threadIdx.x;  // 64 threads
    float p0 = pooled[(size_t)g * 128 + t];
    float p1 = pooled[(size_t)g * 128 + t + 64];
    float a0 = p0 * Wl[t * 2 + 0] + p1 * Wl[(t + 64) * 2 + 0];
    float a1 = p0 * Wl[t * 2 + 1] + p1 * Wl[(t + 64) * 2 + 1];
#pragma unroll
    for (int off = 32; off > 0; off >>= 1) {
        a0 += __shfl_down(a0, off);
        a1 += __shfl_down(a1, off);
    }
    if (t == 0) {
        out[g * 2 + 0] = a0 + bl[0];
        out[g * 2 + 1] = a1 + bl[1];
    }
}

// ---------------- launch ----------------

extern "C" void kernel_launch(void* const* d_in, const int* in_sizes, int n_in,
                              void* d_out, int out_size, void* d_ws, size_t ws_size,
                              hipStream_t stream) {
    const float* x  = (const float*)d_in[0];
    const int*   ei = (const int*)d_in[1];
    const int*   batch = (const int*)d_in[2];
    const float* W1 = (const float*)d_in[3];
    const float* b1 = (const float*)d_in[4];
    const float* W2 = (const float*)d_in[5];
    const float* b2 = (const float*)d_in[6];
    const float* W3 = (const float*)d_in[7];
    const float* b3 = (const float*)d_in[8];
    const float* Wl = (const float*)d_in[9];
    const float* bl = (const float*)d_in[10];
    float* out = (float*)d_out;

    const int N = N_NODES, E = N_EDGES;

    // workspace layout
    char* ws = (char*)d_ws;
    __half* bufA = (__half*)ws;                             // N*128 fp16 (hw)
    __half* bufB = bufA + (size_t)N * 128;                  // N*128 fp16 (agg)
    unsigned* pooled = (unsigned*)(bufB + (size_t)N * 128); // G*128
    float* dis  = (float*)(pooled + (size_t)N_GRAPHS * 128);
    float* dinv = dis + N;
    int*   rowptr = (int*)(dinv + N);                       // N+1
    int*   bkcnt  = rowptr + N + 2;                         // NBK (<=512)
    int*   bkoff  = bkcnt + 512;                            // NBK+1
    int*   bcur   = bkoff + 512;                            // NBK
    int*   csrc   = bcur + 512;                             // E
    unsigned* pk  = (unsigned*)(csrc + E);                  // E (DEAD after passB)
    float* x8   = (float*)pk;                               // N*8 (aliases pk — only valid AFTER passB)
    float* aggx = x8 + (size_t)N * 8;                       // N*8 (aliases pk)
    __half* w2h = (__half*)(pk + E);                        // 128*128 fp16
    __half* w3h = w2h + 128 * 128;                          // 128*128 fp16

    // misc: prepW + zero(bkcnt) + zero(pooled) — one launch (padx NOT here: pk alive)
    k_misc<<<(N_GRAPHS * 128 + 255) / 256, 256, 0, stream>>>(W2, W3, w2h, w3h, bkcnt, pooled);

    // CSR build + norms (bucket hist -> scan -> radix passA/passB)
    int nseg = (E + SEG - 1) / SEG;   // 391
    k_bhist<<<nseg, 256, 0, stream>>>(ei + E, E, bkcnt);
    k_bscan<<<1, 512, 0, stream>>>(bkcnt, bkoff, bcur, E);
    k_passA<<<nseg, 256, 0, stream>>>(ei, bcur, pk, E);
    k_passB<<<NBK, 256, 0, stream>>>(pk, bkoff, rowptr, dis, dinv, csrc, N, E);

    int ggrid = (N + 15) / 16;         // 4 nodes/wave, 4 waves/block = 6250
    int mfma_grid = (N + 63) / 64;     // 1563, 3 blocks/CU

    // layer 1: pad x (pk now dead), aggregate raw x (7ch), fused (aggx@W1 -> relu -> @W2)
    k_padx<<<(N * 8 + 255) / 256, 256, 0, stream>>>(x, x8, N);
    k_gather7<<<(N * 4 + 255) / 256, 256, 0, stream>>>(rowptr, csrc, dis, dinv,
                                                       (const float2*)x8, (float2*)aggx, N);
    k_l12<<<mfma_grid, 256, 0, stream>>>((const float2*)aggx, b1, W1, w2h, bufA, N);

    // layer 2
    k_gather<<<ggrid, 256, 0, stream>>>(rowptr, csrc, dis, dinv,
                                        (const uint4*)bufA, (uint4*)bufB, N);
    k_gemm_mfma<<<mfma_grid, 256, 0, stream>>>(bufB, b2, w3h, bufA, N);

    // layer 3: gather then standalone pool (atomics off the gather's critical path)
    k_gather<<<ggrid, 256, 0, stream>>>(rowptr, csrc, dis, dinv,
                                        (const uint4*)bufA, (uint4*)bufB, N);
    k_pool_max<<<(N * 128 + 255) / 256, 256, 0, stream>>>(bufB, b3, batch, pooled, N);

    // head
    k_final<<<N_GRAPHS, 64, 0, stream>>>((const float*)pooled, Wl, bl, out);
}